// Round 8
// baseline (59777.936 us; speedup 1.0000x reference)
//
#include <hip/hip_runtime.h>

#define NBLK 256
#define NTHR 512
#define NLB 64   // fat LSTM blocks

constexpr int kNMel = 80, kArnn = 1024, kAdim = 128, kEmb = 512, kPre = 256;
constexpr int kNF = 32, kKS = 31, kB = 32, kNctx = 512, kT = 500, kPad = 15;

constexpr int KT_A = 56;   // 1792/32 k-tiles (aLSTM: 256 prenet + 512 actx + 1024 ah)
constexpr int KT_D = 80;   // 2560/32 k-tiles (dLSTM: 1024 ah + 512 actx + 1024 dh)
constexpr int KT_ALL = KT_A + KT_D;

// ---- workspace layout (float offsets); GMB last so it is optional ----
constexpr int OFF_PREB   = 0;                                    // bf16 [500][32][256]
constexpr int OFF_PROCMB = OFF_PREB + kT * kB * kPre / 2;        // bf16 [32*512][128]
constexpr int OFF_QWTB   = OFF_PROCMB + kB * kNctx * kAdim / 2;  // bf16 [128][1024]
constexpr int OFF_LWT    = OFF_QWTB + kAdim * kArnn / 2;         // f32 [128*33]
constexpr int OFF_STATE  = OFF_LWT + kAdim * 33;
constexpr int OFF_AHB    = OFF_STATE;                            // bf16 [2][32][1024]
constexpr int OFF_DHB    = OFF_AHB + 2 * kB * kArnn / 2;         // bf16 [2][32][1024]
constexpr int OFF_DH     = OFF_DHB + 2 * kB * kArnn / 2;         // f32 [2][32][1024]
constexpr int OFF_AC     = OFF_DH + 2 * kB * kArnn;              // f32 [32][1024]
constexpr int OFF_DC     = OFF_AC + kB * kArnn;
constexpr int OFF_ACTX   = OFF_DC + kB * kArnn;                  // f32 [32][512]
constexpr int OFF_AW     = OFF_ACTX + kB * kEmb;                 // f32 [32][512]
constexpr int OFF_AWC    = OFF_AW + kB * kNctx;
constexpr int OFF_PAW    = OFF_AWC + kB * kNctx;                 // block-private
constexpr int OFF_NUM    = OFF_PAW + kB * kNctx;                 // f32 [2][32][512]
constexpr int OFF_DEN    = OFF_NUM + 2 * kB * kEmb;              // f32 [2][32]
constexpr int OFF_END    = OFF_DEN + 2 * kB;
constexpr int STATE_SZ   = OFF_END - OFF_STATE;
// barrier region: one 128B line per word (per-block flags, wake replicas, init)
constexpr int OFF_BAR    = OFF_END;
constexpr int BAR_LINES  = 266;
constexpr int OFF_PAN    = OFF_BAR + BAR_LINES * 32;             // bf16 panels
constexpr int PAN_SZ     = NLB * 4 * KT_ALL * 256;               // floats (same bytes as before)
constexpr int OFF_GMB    = OFF_PAN + PAN_SZ;                     // bf16 [32*512][512] (optional)
constexpr int GMB_SZ     = kB * kNctx * kEmb / 2;

typedef __attribute__((ext_vector_type(4))) float fvec4;
typedef __attribute__((ext_vector_type(8))) short bh8_t;
typedef unsigned long long u64;
typedef unsigned short ushortt;

union U64u { u64 u; float2 f2; ushortt s[4]; };

// shared LDS image for phase X (ushort offsets): 8 chunks x 2048 ushorts each
constexpr int AH_O = 0;        // ah cols 0..511 (half1) / 512..1023 (half2)
constexpr int DH_O = 16384;    // dh cols 0..511 / 512..1023
constexpr int AX_O = 32768;    // actx cols 0..511 (bf16, pre-scaled)

union SMem {
  struct { ushortt stage[49152];                        // 96 KB image
           float zs[8][2][64][4];                       // 16 KB per-wave z
           float hb[2][32][16]; } x1;                   // 4 KB h gather
  struct { float ahb_s[kArnn]; float vw_s[kAdim]; float psum[512]; float q_s[kAdim];
           float aw_s[96]; float awc_s[96]; float cw[kNF * 2 * kKS];
           float loc_s[64 * 33]; float p_s[64]; float lwt[kAdim * 33];
           float dhc[kArnn + kEmb]; float pprj[126];
           ushortt pm[64 * kAdim]; } b;
  struct { float x8[8][80]; float h1[8][256]; } p;
  struct { float mem_s[4][512]; } m;
};

__device__ __forceinline__ float sigf(float x) { return 1.0f / (1.0f + __expf(-x)); }
__device__ __forceinline__ float tanhfast(float x) { return 1.0f - 2.0f / (__expf(2.0f * x) + 1.0f); }

__device__ __forceinline__ ushortt bf16rn(float f) {
  unsigned u = __float_as_uint(f);
  unsigned r = (u + 0x7FFFu + ((u >> 16) & 1u)) >> 16;
  return (ushortt)r;
}
__device__ __forceinline__ float bf2f(ushortt v) {
  return __uint_as_float((unsigned)v << 16);
}

// relaxed agent-scope atomics: cross-XCD coherent, no cache-invalidation side effects
__device__ __forceinline__ u64 ald64(const void* p) {
  return __hip_atomic_load((const u64*)p, __ATOMIC_RELAXED, __HIP_MEMORY_SCOPE_AGENT);
}
__device__ __forceinline__ float alf(const float* p) {
  return __hip_atomic_load(p, __ATOMIC_RELAXED, __HIP_MEMORY_SCOPE_AGENT);
}
__device__ __forceinline__ void asf(float* p, float v) {
  __hip_atomic_store(p, v, __ATOMIC_RELAXED, __HIP_MEMORY_SCOPE_AGENT);
}
__device__ __forceinline__ void as64(void* p, u64 v) {
  __hip_atomic_store((u64*)p, v, __ATOMIC_RELAXED, __HIP_MEMORY_SCOPE_AGENT);
}
__device__ __forceinline__ unsigned alu(const unsigned* p) {
  return __hip_atomic_load(p, __ATOMIC_RELAXED, __HIP_MEMORY_SCOPE_AGENT);
}
__device__ __forceinline__ void asu(unsigned* p, unsigned v) {
  __hip_atomic_store(p, v, __ATOMIC_RELAXED, __HIP_MEMORY_SCOPE_AGENT);
}

// heavyweight init barrier (acq/rel) — used twice, before the scan
__device__ __forceinline__ void gbar_full(unsigned* cnt, unsigned* gen, unsigned& genv) {
  __syncthreads();
  if (threadIdx.x == 0) {
    __threadfence();
    unsigned arrived = __hip_atomic_fetch_add(cnt, 1u, __ATOMIC_ACQ_REL, __HIP_MEMORY_SCOPE_AGENT) + 1u;
    if (arrived == (unsigned)NBLK) {
      __hip_atomic_store(cnt, 0u, __ATOMIC_RELAXED, __HIP_MEMORY_SCOPE_AGENT);
      __hip_atomic_fetch_add(gen, 1u, __ATOMIC_ACQ_REL, __HIP_MEMORY_SCOPE_AGENT);
    } else {
      while (__hip_atomic_load(gen, __ATOMIC_ACQUIRE, __HIP_MEMORY_SCOPE_AGENT) == genv) {
        __builtin_amdgcn_s_sleep(2);
      }
    }
    ++genv;
  }
  __syncthreads();
}

// lightweight scan barrier: per-block flag lines; block 0 sweeps, fans out wake gen
__device__ __forceinline__ void gbar_light(unsigned* bar, unsigned target, int bk, int tid) {
  asm volatile("s_waitcnt vmcnt(0) lgkmcnt(0)" ::: "memory");
  __syncthreads();
  if (bk == 0) {
    if (tid < 64) {
      if (tid == 0) asm volatile("s_waitcnt vmcnt(0)" ::: "memory");
      unsigned i0 = (unsigned)tid * 4, i1 = i0 + 1, i2 = i0 + 2, i3 = i0 + 3;
      for (;;) {
        bool ok = true;
        if (i0 != 0) ok = ok && (alu(&bar[i0 * 32]) >= target);
        ok = ok && (alu(&bar[i1 * 32]) >= target);
        ok = ok && (alu(&bar[i2 * 32]) >= target);
        ok = ok && (alu(&bar[i3 * 32]) >= target);
        if (__all(ok)) break;
        __builtin_amdgcn_s_sleep(1);
      }
      if (tid < 8) asu(&bar[(256 + tid) * 32], target);
    }
  } else {
    if (tid == 0) {
      asm volatile("s_waitcnt vmcnt(0)" ::: "memory");
      asu(&bar[bk * 32], target);
      unsigned* wk = &bar[(256 + (bk & 7)) * 32];
      while (alu(wk) < target) __builtin_amdgcn_s_sleep(1);
    }
  }
  __syncthreads();
}

// ---- phase X staging (R7-proven): whole-block cooperative, deep-issued ----
__device__ __forceinline__ void stage_half1(int tid, const ushortt* __restrict__ AHBq,
    const ushortt* __restrict__ DHBp, const float* __restrict__ numq,
    const float* __restrict__ invden, ushortt* __restrict__ lds)
{
  const int uc = tid & 127;          // 8B col-unit within 512-col region
  const int r0 = tid >> 7;           // 0..3
  const int chunk = uc >> 4, u8c = uc & 15;
  u64 va[8], vd[8], ax[8];
  #pragma unroll
  for (int i = 0; i < 8; ++i) {
    int row = r0 + 4 * i;
    va[i] = ald64(AHBq + (size_t)row * 1024 + uc * 4);
    vd[i] = ald64(DHBp + (size_t)row * 1024 + uc * 4);
  }
  #pragma unroll
  for (int i = 0; i < 8; ++i) {
    int row = r0 + 4 * i;
    const float* np = numq + (size_t)row * 512 + uc * 4;
    U64u a, b; a.u = ald64(np); b.u = ald64(np + 2);
    float s = invden[row];
    U64u pk;
    pk.s[0] = bf16rn(a.f2.x * s);  pk.s[1] = bf16rn(a.f2.y * s);
    pk.s[2] = bf16rn(b.f2.x * s);  pk.s[3] = bf16rn(b.f2.y * s);
    ax[i] = pk.u;
  }
  #pragma unroll
  for (int i = 0; i < 8; ++i) {
    int row = r0 + 4 * i;
    int sw = u8c ^ ((row & 7) << 1);
    int off = chunk * 2048 + row * 64 + sw * 4;
    *reinterpret_cast<u64*>(lds + AH_O + off) = va[i];
    *reinterpret_cast<u64*>(lds + DH_O + off) = vd[i];
    *reinterpret_cast<u64*>(lds + AX_O + off) = ax[i];
  }
}
__device__ __forceinline__ void load_half2(int tid, const ushortt* __restrict__ AHBq,
    const ushortt* __restrict__ DHBp, u64* va, u64* vd)
{
  const int uc = tid & 127, r0 = tid >> 7;
  #pragma unroll
  for (int i = 0; i < 8; ++i) {
    int row = r0 + 4 * i;
    va[i] = ald64(AHBq + (size_t)row * 1024 + 512 + uc * 4);
    vd[i] = ald64(DHBp + (size_t)row * 1024 + 512 + uc * 4);
  }
}
__device__ __forceinline__ void write_half2(int tid, const u64* va, const u64* vd,
                                            ushortt* __restrict__ lds)
{
  const int uc = tid & 127, r0 = tid >> 7;
  const int chunk = uc >> 4, u8c = uc & 15;
  #pragma unroll
  for (int i = 0; i < 8; ++i) {
    int row = r0 + 4 * i;
    int sw = u8c ^ ((row & 7) << 1);
    int off = chunk * 2048 + row * 64 + sw * 4;
    *reinterpret_cast<u64*>(lds + AH_O + off) = va[i];
    *reinterpret_cast<u64*>(lds + DH_O + off) = vd[i];
  }
}

// LDS chunk base (ushorts) for a k-tile (R7-proven mapping)
__device__ constexpr int lds_base(int LS, int kt) {
  if (LS == 0) {
    if (kt < 24) return AX_O + ((kt - 8) >> 1) * 2048;
    if (kt < 40) return AH_O + ((kt - 24) >> 1) * 2048;
    return AH_O + ((kt - 40) >> 1) * 2048;
  } else {
    if (kt < 16) return AH_O + (kt >> 1) * 2048;
    if (kt < 32) return AH_O + ((kt - 16) >> 1) * 2048;
    if (kt < 48) return AX_O + ((kt - 32) >> 1) * 2048;
    if (kt < 64) return DH_O + ((kt - 48) >> 1) * 2048;
    return DH_O + ((kt - 64) >> 1) * 2048;
  }
}

// one wave's half-pass over one LSTM: single n-tile, single m-half, all listed k-tiles
template<int LS, int HALF>
__device__ __forceinline__ void lstm_half(const ushortt* __restrict__ lds,
    const short* __restrict__ panw, const ushortt* __restrict__ preb_t,
    int row, int m, int kg, int l, fvec4& z)
{
  constexpr int N = (LS == 0) ? (HALF == 0 ? 32 : 24) : (HALF == 0 ? 48 : 32);
  #pragma unroll
  for (int i = 0; i < N; ++i) {
    int kt;
    if (LS == 0) kt = (HALF == 0) ? (8 + i) : (i < 8 ? i : 32 + i);
    else         kt = (HALF == 0) ? (i < 16 ? i : i + 16) : (i < 16 ? 16 + i : 48 + i);
    bh8_t f = *reinterpret_cast<const bh8_t*>(panw + (size_t)((LS ? KT_A : 0) + kt) * 512 + l * 8);
    bh8_t a;
    if (LS == 0 && kt < 8) {
      a = *reinterpret_cast<const bh8_t*>(preb_t + (size_t)row * kPre + kt * 32 + kg * 8);
    } else {
      const int base = lds_base(LS, kt);
      const int sw = (2 * ((kt & 1) * 4 + kg)) ^ ((m & 7) << 1);
      a = *reinterpret_cast<const bh8_t*>(lds + base + row * 64 + sw * 4);
    }
    z = __builtin_amdgcn_mfma_f32_16x16x32_bf16(a, f, z, 0, 0, 0);
  }
}

extern "C" __global__ void __launch_bounds__(NTHR, 1)
decoder_kernel(const float* __restrict__ gmem, const float* __restrict__ dec,
               const unsigned char* __restrict__ mask,
               const float* __restrict__ pw1, const float* __restrict__ pw2,
               const float* __restrict__ awih, const float* __restrict__ awhh,
               const float* __restrict__ abih, const float* __restrict__ abhh,
               const float* __restrict__ qw, const float* __restrict__ mw,
               const float* __restrict__ cvw, const float* __restrict__ locw,
               const float* __restrict__ vw,
               const float* __restrict__ dwih, const float* __restrict__ dwhh,
               const float* __restrict__ dbih, const float* __restrict__ dbhh,
               const float* __restrict__ pjw, const float* __restrict__ pjb,
               const float* __restrict__ gw, const float* __restrict__ gb,
               float* __restrict__ out, float* __restrict__ ws, int useg)
{
  __shared__ SMem sm;
  __shared__ float s_invden[32];
  const int bk = blockIdx.x, tid = threadIdx.x;
  unsigned genv_f = 0, bcnt = 0;
  unsigned* bar = reinterpret_cast<unsigned*>(ws + OFF_BAR);
  unsigned* cntF = &bar[264 * 32];
  unsigned* genF = &bar[265 * 32];

  ushortt* PREBu = reinterpret_cast<ushortt*>(ws + OFF_PREB);
  ushortt* PROCMBu = reinterpret_cast<ushortt*>(ws + OFF_PROCMB);
  ushortt* QWTBu = reinterpret_cast<ushortt*>(ws + OFF_QWTB);
  float* LWT = ws + OFF_LWT;
  ushortt* AHBu = reinterpret_cast<ushortt*>(ws + OFF_AHB);
  ushortt* DHBu = reinterpret_cast<ushortt*>(ws + OFF_DHB);
  float* DH = ws + OFF_DH;
  float* AC = ws + OFF_AC;
  float* DC = ws + OFF_DC;
  float* ACTX = ws + OFF_ACTX;
  float* AWp = ws + OFF_AW;
  float* AWC = ws + OFF_AWC;
  float* PAW = ws + OFF_PAW;
  float* NUM = ws + OFF_NUM;
  float* DEN = ws + OFF_DEN;
  short* PANS = reinterpret_cast<short*>(ws + OFF_PAN);
  ushortt* GMB = reinterpret_cast<ushortt*>(ws + OFF_GMB);

  // ---------------- P0: zero state + QWTB + LWT ----------------
  for (int i = bk * NTHR + tid; i < STATE_SZ; i += NBLK * NTHR) (ws + OFF_STATE)[i] = 0.f;
  for (int i = bk * NTHR + tid; i < kAdim * kArnn; i += NBLK * NTHR)
    QWTBu[i] = bf16rn(qw[i]);
  for (int i = bk * NTHR + tid; i < kAdim * kNF; i += NBLK * NTHR) {
    int d = i >> 5, f = i & 31;
    LWT[d * 33 + f] = locw[i];
  }
  gbar_full(cntF, genF, genv_f);

  // ---------------- P1: den init, proc_mem (+bf16 gmem copy), prenet, panels ----------------
  if (bk == 0 && tid < 2 * kB) asf(&DEN[tid], 1.0f);
  for (int it = 0; it < 16; ++it) {
    int task0 = bk * 64 + it * 4;
    for (int i = tid; i < 2048; i += NTHR) {
      int pr = i >> 9, h = i & 511;
      sm.m.mem_s[pr][h] = gmem[(size_t)(task0 + pr) * kEmb + h];
    }
    __syncthreads();
    {
      int pr = tid >> 7, d = tid & 127;
      const float* mwr = mw + d * kEmb;
      float acc = 0.f;
      for (int h = 0; h < kEmb; ++h) acc = fmaf(sm.m.mem_s[pr][h], mwr[h], acc);
      PROCMBu[(size_t)(task0 + pr) * kAdim + d] = bf16rn(acc);
    }
    if (useg) {
      for (int i = tid; i < 2048; i += NTHR) {
        int pr = i >> 9, h = i & 511;
        GMB[(size_t)(task0 + pr) * kEmb + h] = bf16rn(sm.m.mem_s[pr][h]);
      }
    }
    __syncthreads();
  }
  for (int g = bk; g < 2000; g += NBLK) {
    int t_idx = g >> 2;
    int b0 = (g & 3) * 8;
    if (t_idx == 0) {
      for (int i = tid; i < 8 * kPre; i += NTHR)
        PREBu[(size_t)(b0 + (i >> 8)) * kPre + (i & 255)] = 0;
      continue;
    }
    for (int i = tid; i < 640; i += NTHR) {
      int bb = i / 80, m2 = i % 80;
      sm.p.x8[bb][m2] = dec[((size_t)(b0 + bb) * kNMel + m2) * kT + (t_idx - 1)];
    }
    __syncthreads();
    {
      int u = tid & 255, rep = tid >> 8;
      float acc[4] = {0.f, 0.f, 0.f, 0.f};
      for (int m2 = 0; m2 < 80; ++m2) {
        float w = pw1[u * kNMel + m2];
        #pragma unroll
        for (int r = 0; r < 4; ++r) acc[r] = fmaf(w, sm.p.x8[rep * 4 + r][m2], acc[r]);
      }
      #pragma unroll
      for (int r = 0; r < 4; ++r) sm.p.h1[rep * 4 + r][u] = fmaxf(acc[r], 0.f);
    }
    __syncthreads();
    {
      int u = tid & 255, rep = tid >> 8;
      float acc[4] = {0.f, 0.f, 0.f, 0.f};
      for (int k = 0; k < kPre; ++k) {
        float w = pw2[u * kPre + k];
        #pragma unroll
        for (int r = 0; r < 4; ++r) acc[r] = fmaf(w, sm.p.h1[rep * 4 + r][k], acc[r]);
      }
      #pragma unroll
      for (int r = 0; r < 4; ++r)
        PREBu[((size_t)t_idx * kB + b0 + rep * 4 + r) * kPre + u] = bf16rn(fmaxf(acc[r], 0.f));
    }
    __syncthreads();
  }
  {  // pack bf16 weight panels: [lb][nt][kta][lane] so each wave streams contiguously
    const int UNITS = NLB * 4 * KT_ALL * 64;
    for (int u = bk * NTHR + tid; u < UNITS; u += NBLK * NTHR) {
      int lb = u / (4 * KT_ALL * 64);
      int rem = u - lb * (4 * KT_ALL * 64);
      int nt = rem / (KT_ALL * 64);
      rem -= nt * (KT_ALL * 64);
      int kta = rem >> 6, l = rem & 63;
      int lstm = (kta >= KT_A);
      int kt = lstm ? kta - KT_A : kta;
      int n = l & 15, kg = l >> 4;
      int r = (n >> 2) * 1024 + lb * 16 + nt * 4 + (n & 3);
      bh8_t v;
      #pragma unroll
      for (int j = 0; j < 8; ++j) {
        int k = kt * 32 + kg * 8 + j;
        float wv;
        if (!lstm) wv = (k < 768) ? awih[(size_t)r * 768 + k] : awhh[(size_t)r * 1024 + (k - 768)];
        else       wv = (k < 1536) ? dwih[(size_t)r * 1536 + k] : dwhh[(size_t)r * 1024 + (k - 1536)];
        v[j] = (short)bf16rn(wv);
      }
      *reinterpret_cast<bh8_t*>(PANS + (size_t)u * 8) = v;
    }
  }
  gbar_full(cntF, genF, genv_f);

  // ---------------- main scan: 2 barriers/step ----------------
  for (int t = 0; t <= kT; ++t) {
    const int p = t & 1, q = p ^ 1;
    float* nump = NUM + p * kB * kEmb;
    const float* numq = NUM + q * kB * kEmb;
    const ushortt* AHBq_ = AHBu + q * kB * kArnn;
    const ushortt* DHBp_ = DHBu + p * kB * kArnn;

    // ---- phase X: finalize(t-1) on all blocks; LSTMs on blocks 0..63 ----
    if (tid < kB) s_invden[tid] = 1.0f / alf(DEN + q * kB + tid);
    __syncthreads();
    if (t > 0 && tid < 64) {
      int idx = bk * 64 + tid;
      int b2 = idx >> 9;
      float invd = s_invden[b2];
      float av = PAW[idx] * invd;
      asf(&AWp[idx], av);
      asf(&AWC[idx], alf(&AWC[idx]) + av);
      asf(&ACTX[idx], alf(&numq[idx]) * invd);
    }
    if (t < kT) {
      if (tid < 64) asf(&nump[bk * 64 + tid], 0.f);
      if (bk == 0 && tid < kB) asf(DEN + p * kB + tid, 0.f);
    }
    if (bk < NLB) {
      ushortt* XL = reinterpret_cast<ushortt*>(&sm);
      stage_half1(tid, AHBq_, DHBp_, numq, s_invden, XL);
      u64 vA2[8], vD2[8];
      load_half2(tid, AHBq_, DHBp_, vA2, vD2);
      __syncthreads();
      const int w8 = tid >> 6, l = tid & 63;
      const int nt = w8 & 3, mh = w8 >> 2;
      const int m = l & 15, kg = l >> 4, row = mh * 16 + m;
      fvec4 za = {0.f, 0.f, 0.f, 0.f}, zd = za;
      const ushortt* preb_t = PREBu + (size_t)t * kB * kPre;
      const short* panw = PANS + (size_t)(bk * 4 + nt) * KT_ALL * 512;
      if (t < kT) lstm_half<0, 0>(XL, panw, preb_t, row, m, kg, l, za);
      if (t > 0)  lstm_half<1, 0>(XL, panw, preb_t, row, m, kg, l, zd);
      __syncthreads();
      write_half2(tid, vA2, vD2, XL);
      __syncthreads();
      if (t < kT) lstm_half<0, 1>(XL, panw, preb_t, row, m, kg, l, za);
      if (t > 0)  lstm_half<1, 1>(XL, panw, preb_t, row, m, kg, l, zd);
      __syncthreads();   // image dead; zs/hb live in separate region
      *reinterpret_cast<fvec4*>(&sm.x1.zs[w8][0][l][0]) = za;
      *reinterpret_cast<fvec4*>(&sm.x1.zs[w8][1][l][0]) = zd;
      __syncthreads();
      {  // in-wave gate epilogue: lane -> (batch, unit)
        const int u4 = l & 3, bi = l >> 2, b = mh * 16 + bi;
        const int col = bk * 16 + nt * 4 + u4;
        const int lsrc = (bi >> 2) * 16, jsrc = bi & 3;
        const int idx = b * kArnn + col;
        if (t < kT) {
          float zg[4];
          #pragma unroll
          for (int g = 0; g < 4; ++g) {
            int rg = g * 1024 + col;
            zg[g] = sm.x1.zs[w8][0][lsrc + g * 4 + u4][jsrc] + abih[rg] + abhh[rg];
          }
          float c = sigf(zg[1]) * AC[idx] + sigf(zg[0]) * tanhfast(zg[2]);
          AC[idx] = c;
          sm.x1.hb[0][b][nt * 4 + u4] = sigf(zg[3]) * tanhfast(c);
        }
        if (t > 0) {
          float zg[4];
          #pragma unroll
          for (int g = 0; g < 4; ++g) {
            int rg = g * 1024 + col;
            zg[g] = sm.x1.zs[w8][1][lsrc + g * 4 + u4][jsrc] + dbih[rg] + dbhh[rg];
          }
          float c = sigf(zg[1]) * DC[idx] + sigf(zg[0]) * tanhfast(zg[2]);
          DC[idx] = c;
          float h = sigf(zg[3]) * tanhfast(c);
          sm.x1.hb[1][b][nt * 4 + u4] = h;
          asf(&DH[q * kB * kArnn + idx], h);
        }
      }
      __syncthreads();
      if (tid < 256) {  // pack h -> bf16 state (4 units per as64)
        int ls = tid >> 7, rem = tid & 127, b = rem >> 2, q4 = rem & 3;
        bool go2 = ls ? (t > 0) : (t < kT);
        if (go2) {
          U64u pk;
          #pragma unroll
          for (int j = 0; j < 4; ++j) pk.s[j] = bf16rn(sm.x1.hb[ls][b][q4 * 4 + j]);
          ushortt* dst = (ls ? (DHBu + q * kB * kArnn) : (AHBu + p * kB * kArnn))
                         + b * kArnn + bk * 16 + q4 * 4;
          as64(dst, pk.u);
        }
      }
    }
    gbar_light(bar, ++bcnt, bk, tid);

    if (t < kT) {
      // ---- phase B: attention step t (+ mel/gate of t-1) ----
      const int b = bk >> 3, sub = bk & 7, j0 = sub * 64;
      const int pbase = (sub == 0) ? 0 : 21 + (sub - 1) * 20;
      const int pcnt = (sub == 0) ? 21 : 20;
      const ushortt* AHBp_ = AHBu + p * kB * kArnn;
      // S1: staging
      if (tid < 256) {
        U64u v; v.u = ald64(AHBp_ + b * kArnn + tid * 4);
        #pragma unroll
        for (int j = 0; j < 4; ++j) sm.b.ahb_s[tid * 4 + j] = bf2f(v.s[j]);
      }
      for (int i = tid; i < 94; i += NTHR) {
        int jj = j0 - kPad + i;
        bool ok = (jj >= 0 && jj < kNctx);
        sm.b.aw_s[i] = ok ? alf(&AWp[b * kNctx + jj]) : 0.f;
        sm.b.awc_s[i] = ok ? alf(&AWC[b * kNctx + jj]) : 0.f;
      }
      for (int i = tid; i < kNF * 2 * kKS; i += NTHR) sm.b.cw[i] = cvw[i];
      for (int i = tid; i < kAdim * 33; i += NTHR) sm.b.lwt[i] = LWT[i];
      for (int i = tid; i < kAdim; i += NTHR) sm.b.vw_s[i] = vw[i];
      {  // proc_mem tile (bf16)
        const fvec4* src = reinterpret_cast<const fvec4*>(PROCMBu + (size_t)(b * kNctx + j0) * kAdim);
        fvec4* dst = reinterpret_cast<fvec4*>(sm.b.pm);
        for (int i = tid; i < 1024; i += NTHR) dst[i] = src[i];
      }
      if (sub < 4 && t > 0) {
        for (int i = tid; i < kArnn + kEmb; i += NTHR)
          sm.b.dhc[i] = (i < kArnn) ? alf(&DH[q * kB * kArnn + b * kArnn + i])
                                    : alf(&ACTX[b * kEmb + (i - kArnn)]);
      }
      __syncthreads();
      // S2: q partial (4-way K split, contiguous bf16 weights)
      {
        int d = tid & 127, qr = tid >> 7;
        const ushortt* wq = QWTBu + (size_t)d * kArnn + qr * 256;
        const float* ahs = sm.b.ahb_s + qr * 256;
        float acc = 0.f;
        #pragma unroll 4
        for (int h8 = 0; h8 < 32; ++h8) {
          U64u a, c2;
          a.u = *reinterpret_cast<const u64*>(wq + h8 * 8);
          c2.u = *reinterpret_cast<const u64*>(wq + h8 * 8 + 4);
          #pragma unroll
          for (int j = 0; j < 4; ++j) acc = fmaf(bf2f(a.s[j]), ahs[h8 * 8 + j], acc);
          #pragma unroll
          for (int j = 0; j < 4; ++j) acc = fmaf(bf2f(c2.s[j]), ahs[h8 * 8 + 4 + j], acc);
        }
        sm.b.psum[tid] = acc;
      }
      __syncthreads();
      // S3: q reduce + conv + projection partials
      if (tid < kAdim)
        sm.b.q_s[tid] = sm.b.psum[tid] + sm.b.psum[128 + tid]
                      + sm.b.psum[256 + tid] + sm.b.psum[384 + tid];
      {
        int j = tid >> 3, f0 = (tid & 7) * 4;
        #pragma unroll
        for (int fi = 0; fi < 4; ++fi) {
          int f = f0 + fi;
          const float* w0 = &sm.b.cw[f * 62];
          float s = 0.f;
          for (int k = 0; k < kKS; ++k)
            s = fmaf(sm.b.aw_s[j + k], w0[k], fmaf(sm.b.awc_s[j + k], w0[31 + k], s));
          sm.b.loc_s[j * 33 + f] = s;
        }
      }
      if (sub < 4 && t > 0 && tid < pcnt * 6) {
        int ol = tid / 6, kc = tid % 6, og = pbase + ol;
        const float* row = (og < kNMel) ? pjw + (size_t)og * (kArnn + kEmb) : gw;
        const float* x = sm.b.dhc + kc * 256;
        const float* r2 = row + kc * 256;
        float acc = 0.f;
        for (int k = 0; k < 256; ++k) acc = fmaf(r2[k], x[k], acc);
        sm.b.pprj[tid] = acc;
      }
      __syncthreads();
      // S4: energies + exp; projection finals
      {
        int j = tid >> 3, grp = tid & 7, jj = j0 + j;
        float pe = 0.f;
        #pragma unroll 4
        for (int dd = 0; dd < 16; ++dd) {
          int d = grp + 8 * dd;
          float l2 = 0.f;
          const float* ls2 = &sm.b.loc_s[j * 33];
          const float* lw2 = &sm.b.lwt[d * 33];
          #pragma unroll 8
          for (int f = 0; f < kNF; ++f) l2 = fmaf(ls2[f], lw2[f], l2);
          float x = sm.b.q_s[d] + bf2f(sm.b.pm[j * kAdim + d]) + l2;
          pe = fmaf(sm.b.vw_s[d], tanhfast(x), pe);
        }
        pe += __shfl_xor(pe, 1);
        pe += __shfl_xor(pe, 2);
        pe += __shfl_xor(pe, 4);
        if (grp == 0) {
          float pv = mask[b * kNctx + jj] ? 0.f : __expf(pe);
          sm.b.p_s[j] = pv;
          PAW[b * kNctx + jj] = pv;   // block-private
        }
      }
      if (sub < 4 && t > 0 && tid < pcnt) {
        int og = pbase + tid;
        float val = (og < kNMel) ? pjb[og] : gb[0];
        #pragma unroll
        for (int kc = 0; kc < 6; ++kc) val += sm.b.pprj[tid * 6 + kc];
        if (og < kNMel) out[((size_t)b * kNMel + og) * kT + (t - 1)] = val;
        else out[(size_t)kB * kNMel * kT + b * kT + (t - 1)] = val;
      }
      __syncthreads();
      // S5: denominator + numerator (parity-p buffers)
      if (tid < 64) {
        float v = sm.b.p_s[tid];
        #pragma unroll
        for (int o = 1; o < 64; o <<= 1) v += __shfl_xor(v, o);
        if (tid == 0) atomicAdd(DEN + p * kB + b, v);
      }
      if (useg) {
        const ushortt* memb = GMB + (size_t)(b * kNctx + j0) * kEmb + tid;
        float a0 = 0.f, a1 = 0.f, a2 = 0.f, a3 = 0.f;
        #pragma unroll 4
        for (int jj2 = 0; jj2 < 64; jj2 += 4) {
          a0 = fmaf(sm.b.p_s[jj2],     bf2f(memb[(size_t)jj2 * kEmb]), a0);
          a1 = fmaf(sm.b.p_s[jj2 + 1], bf2f(memb[(size_t)(jj2 + 1) * kEmb]), a1);
          a2 = fmaf(sm.b.p_s[jj2 + 2], bf2f(memb[(size_t)(jj2 + 2) * kEmb]), a2);
          a3 = fmaf(sm.b.p_s[jj2 + 3], bf2f(memb[(size_t)(jj2 + 3) * kEmb]), a3);
        }
        atomicAdd(&nump[b * kEmb + tid], (a0 + a1) + (a2 + a3));
      } else {
        const float* memb = gmem + (size_t)(b * kNctx + j0) * kEmb + tid;
        float a0 = 0.f, a1 = 0.f;
        #pragma unroll 8
        for (int jj2 = 0; jj2 < 64; jj2 += 2) {
          a0 = fmaf(sm.b.p_s[jj2], memb[(size_t)jj2 * kEmb], a0);
          a1 = fmaf(sm.b.p_s[jj2 + 1], memb[(size_t)(jj2 + 1) * kEmb], a1);
        }
        atomicAdd(&nump[b * kEmb + tid], a0 + a1);
      }
      gbar_light(bar, ++bcnt, bk, tid);
    }
  }

  // final projection t=499 (dh parity 1; ACTX(499) finalized in phase X(500))
  if (bk < kB) {
    const int b = bk;
    for (int i = tid; i < kArnn + kEmb; i += NTHR)
      sm.b.dhc[i] = (i < kArnn) ? alf(&DH[1 * kB * kArnn + b * kArnn + i])
                                : alf(&ACTX[b * kEmb + (i - kArnn)]);
    __syncthreads();
    if (tid < 486) {
      int ol = tid / 6, kc = tid % 6;
      const float* row = (ol < kNMel) ? pjw + (size_t)ol * (kArnn + kEmb) : gw;
      const float* x = sm.b.dhc + kc * 256;
      const float* r2 = row + kc * 256;
      float acc = 0.f;
      for (int k = 0; k < 256; ++k) acc = fmaf(r2[k], x[k], acc);
      sm.b.psum[tid] = acc;
    }
    __syncthreads();
    if (tid < 81) {
      float val = (tid < kNMel) ? pjb[tid] : gb[0];
      #pragma unroll
      for (int kc = 0; kc < 6; ++kc) val += sm.b.psum[tid * 6 + kc];
      if (tid < kNMel) out[((size_t)b * kNMel + tid) * kT + (kT - 1)] = val;
      else out[(size_t)kB * kNMel * kT + b * kT + (kT - 1)] = val;
    }
  }
}

extern "C" void kernel_launch(void* const* d_in, const int* in_sizes, int n_in,
                              void* d_out, int out_size, void* d_ws, size_t ws_size,
                              hipStream_t stream) {
  const float* gmem = (const float*)d_in[0];
  const float* dec = (const float*)d_in[1];
  const unsigned char* mask = (const unsigned char*)d_in[2];
  const float* pw1 = (const float*)d_in[3];
  const float* pw2 = (const float*)d_in[4];
  const float* awih = (const float*)d_in[5];
  const float* awhh = (const float*)d_in[6];
  const float* abih = (const float*)d_in[7];
  const float* abhh = (const float*)d_in[8];
  const float* qw = (const float*)d_in[9];
  const float* mw = (const float*)d_in[10];
  const float* cvw = (const float*)d_in[11];
  const float* locw = (const float*)d_in[12];
  const float* vw = (const float*)d_in[13];
  const float* dwih = (const float*)d_in[14];
  const float* dwhh = (const float*)d_in[15];
  const float* dbih = (const float*)d_in[16];
  const float* dbhh = (const float*)d_in[17];
  const float* pjw = (const float*)d_in[18];
  const float* pjb = (const float*)d_in[19];
  const float* gw = (const float*)d_in[20];
  const float* gb = (const float*)d_in[21];
  float* out = (float*)d_out;
  float* ws = (float*)d_ws;

  int useg = (ws_size >= (size_t)(OFF_GMB + GMB_SZ) * sizeof(float)) ? 1 : 0;

  // entire barrier region (flags + wake lines + init barrier) must start at 0
  hipMemsetAsync((char*)d_ws + (size_t)OFF_BAR * sizeof(float), 0,
                 (size_t)BAR_LINES * 128, stream);
  hipLaunchKernelGGL(decoder_kernel, dim3(NBLK), dim3(NTHR), 0, stream,
                     gmem, dec, mask, pw1, pw2, awih, awhh, abih, abhh, qw, mw,
                     cvw, locw, vw, dwih, dwhh, dbih, dbhh, pjw, pjb, gw, gb,
                     out, ws, useg);
}

// Round 9
// 41678.717 us; speedup vs baseline: 1.4343x; 1.4343x over previous
//
#include <hip/hip_runtime.h>

#define NBLK 256
#define NTHR 512

constexpr int kNMel = 80, kArnn = 1024, kAdim = 128, kEmb = 512, kPre = 256;
constexpr int kNF = 32, kKS = 31, kB = 32, kNctx = 512, kT = 500, kPad = 15;

constexpr int KT_A = 56;   // 1792/32 k-tiles (aLSTM: 256 prenet + 512 actx + 1024 ah)
constexpr int KT_D = 80;   // 2560/32 k-tiles (dLSTM: 1024 ah + 512 actx + 1024 dh)
constexpr int KT_ALL = KT_A + KT_D;

// ---- workspace layout (float offsets); GMB last so it is optional ----
constexpr int OFF_PREB   = 0;                                    // bf16 [500][32][256]
constexpr int OFF_PROCMB = OFF_PREB + kT * kB * kPre / 2;        // bf16 [32*512][128]
constexpr int OFF_QWTB   = OFF_PROCMB + kB * kNctx * kAdim / 2;  // bf16 [128][1024]
constexpr int OFF_LWT    = OFF_QWTB + kAdim * kArnn / 2;         // f32 [128*33]
constexpr int OFF_STATE  = OFF_LWT + kAdim * 33;
constexpr int OFF_AHB    = OFF_STATE;                            // bf16 [2][32][1024]
constexpr int OFF_DHB    = OFF_AHB + 2 * kB * kArnn / 2;         // bf16 [2][32][1024]
constexpr int OFF_DH     = OFF_DHB + 2 * kB * kArnn / 2;         // f32 [2][32][1024]
constexpr int OFF_AC     = OFF_DH + 2 * kB * kArnn;              // f32 [32][1024]
constexpr int OFF_DC     = OFF_AC + kB * kArnn;
constexpr int OFF_ACTX   = OFF_DC + kB * kArnn;                  // f32 [32][512]
constexpr int OFF_AW     = OFF_ACTX + kB * kEmb;                 // f32 [32][512]
constexpr int OFF_AWC    = OFF_AW + kB * kNctx;
constexpr int OFF_PAW    = OFF_AWC + kB * kNctx;                 // block-private
constexpr int OFF_NUM    = OFF_PAW + kB * kNctx;                 // f32 [2][32][512]
constexpr int OFF_DEN    = OFF_NUM + 2 * kB * kEmb;              // f32 [2][32]
constexpr int OFF_END    = OFF_DEN + 2 * kB;
constexpr int STATE_SZ   = OFF_END - OFF_STATE;
// barrier region: one 128B line per word (per-block flags, wake replicas, init)
constexpr int OFF_BAR    = OFF_END;
constexpr int BAR_LINES  = 266;
constexpr int OFF_PAN    = OFF_BAR + BAR_LINES * 32;             // bf16 panels
constexpr int PAN_SZ     = NBLK * KT_ALL * 256;                  // floats
constexpr int OFF_GMB    = OFF_PAN + PAN_SZ;                     // bf16 [32*512][512] (optional)
constexpr int GMB_SZ     = kB * kNctx * kEmb / 2;

typedef __attribute__((ext_vector_type(4))) float fvec4;
typedef __attribute__((ext_vector_type(8))) short bh8_t;
typedef unsigned long long u64;
typedef unsigned short ushortt;

union U64u { u64 u; float2 f2; ushortt s[4]; };

union SMem {
  struct { ushortt xs[8][2][2048]; } x1;                             // 64 KB staging
  struct { float zra[4][2][64][4]; float zrd[4][2][64][4];
           float hb[2][32][4]; } x2;                                 // overlay after staging dead
  struct { float ahb_s[kArnn]; float vw_s[kAdim]; float psum[512]; float q_s[kAdim];
           float aw_s[96]; float awc_s[96]; float cw[kNF * 2 * kKS];
           float loc_s[64 * 33]; float p_s[64]; float lwt[kAdim * 33];
           float dhc[kArnn + kEmb]; float pprj[126];
           ushortt pm[64 * kAdim]; } b;
  struct { float x8[8][80]; float h1[8][256]; } p;
  struct { float mem_s[4][512]; } m;
};

__device__ __forceinline__ float sigf(float x) { return 1.0f / (1.0f + __expf(-x)); }
__device__ __forceinline__ float tanhfast(float x) { return 1.0f - 2.0f / (__expf(2.0f * x) + 1.0f); }

__device__ __forceinline__ ushortt bf16rn(float f) {
  unsigned u = __float_as_uint(f);
  unsigned r = (u + 0x7FFFu + ((u >> 16) & 1u)) >> 16;
  return (ushortt)r;
}
__device__ __forceinline__ float bf2f(ushortt v) {
  return __uint_as_float((unsigned)v << 16);
}

// relaxed agent-scope atomics: cross-XCD coherent, no cache-invalidation side effects
__device__ __forceinline__ u64 ald64(const void* p) {
  return __hip_atomic_load((const u64*)p, __ATOMIC_RELAXED, __HIP_MEMORY_SCOPE_AGENT);
}
__device__ __forceinline__ float alf(const float* p) {
  return __hip_atomic_load(p, __ATOMIC_RELAXED, __HIP_MEMORY_SCOPE_AGENT);
}
__device__ __forceinline__ void asf(float* p, float v) {
  __hip_atomic_store(p, v, __ATOMIC_RELAXED, __HIP_MEMORY_SCOPE_AGENT);
}
__device__ __forceinline__ void as64(void* p, u64 v) {
  __hip_atomic_store((u64*)p, v, __ATOMIC_RELAXED, __HIP_MEMORY_SCOPE_AGENT);
}
__device__ __forceinline__ unsigned alu(const unsigned* p) {
  return __hip_atomic_load(p, __ATOMIC_RELAXED, __HIP_MEMORY_SCOPE_AGENT);
}
__device__ __forceinline__ void asu(unsigned* p, unsigned v) {
  __hip_atomic_store(p, v, __ATOMIC_RELAXED, __HIP_MEMORY_SCOPE_AGENT);
}

// heavyweight init barrier (acq/rel) — used twice, before the scan
__device__ __forceinline__ void gbar_full(unsigned* cnt, unsigned* gen, unsigned& genv) {
  __syncthreads();
  if (threadIdx.x == 0) {
    __threadfence();
    unsigned arrived = __hip_atomic_fetch_add(cnt, 1u, __ATOMIC_ACQ_REL, __HIP_MEMORY_SCOPE_AGENT) + 1u;
    if (arrived == (unsigned)NBLK) {
      __hip_atomic_store(cnt, 0u, __ATOMIC_RELAXED, __HIP_MEMORY_SCOPE_AGENT);
      __hip_atomic_fetch_add(gen, 1u, __ATOMIC_ACQ_REL, __HIP_MEMORY_SCOPE_AGENT);
    } else {
      while (__hip_atomic_load(gen, __ATOMIC_ACQUIRE, __HIP_MEMORY_SCOPE_AGENT) == genv) {
        __builtin_amdgcn_s_sleep(2);
      }
    }
    ++genv;
  }
  __syncthreads();
}

// lightweight scan barrier: per-block flag lines; block 0 sweeps, fans out wake gen
__device__ __forceinline__ void gbar_light(unsigned* bar, unsigned target, int bk, int tid) {
  asm volatile("s_waitcnt vmcnt(0) lgkmcnt(0)" ::: "memory");
  __syncthreads();
  if (bk == 0) {
    if (tid < 64) {
      if (tid == 0) asm volatile("s_waitcnt vmcnt(0)" ::: "memory");
      unsigned i0 = (unsigned)tid * 4, i1 = i0 + 1, i2 = i0 + 2, i3 = i0 + 3;
      for (;;) {
        bool ok = true;
        if (i0 != 0) ok = ok && (alu(&bar[i0 * 32]) >= target);
        ok = ok && (alu(&bar[i1 * 32]) >= target);
        ok = ok && (alu(&bar[i2 * 32]) >= target);
        ok = ok && (alu(&bar[i3 * 32]) >= target);
        if (__all(ok)) break;
        __builtin_amdgcn_s_sleep(1);
      }
      if (tid < 8) asu(&bar[(256 + tid) * 32], target);
    }
  } else {
    if (tid == 0) {
      asm volatile("s_waitcnt vmcnt(0)" ::: "memory");
      asu(&bar[bk * 32], target);
      unsigned* wk = &bar[(256 + (bk & 7)) * 32];
      while (alu(wk) < target) __builtin_amdgcn_s_sleep(1);
    }
  }
  __syncthreads();
}

// ---- one wave's share of one LSTM step, double-buffered LDS staging + MFMA ----
// LS=0: aLSTM (7 chunks of 64 cols), LS=1: dLSTM (10 chunks). W = wave slot 0..3.
// actx cols are staged from numq (f32) scaled by 1/den per row.
// Panel frags for the tail chunks are loaded non-temporal (stream; keep the head
// resident in L2: resident panel footprint/XCD ~3.1 MB < 4 MB).
template<int LS, int W>
__device__ __forceinline__ void lstm_wave(
    const ushortt* __restrict__ s0, const ushortt* __restrict__ s2,
    const float* __restrict__ numq, const float* __restrict__ invden,
    const short* __restrict__ pan,
    int l, ushortt* xstg, fvec4& z0, fvec4& z1)
{
  constexpr int NC  = LS ? 10 : 7;
  constexpr int NTC = LS ? 7 : 5;               // chunks >= NTC load panels non-temporal
  constexpr int CB  = LS ? W * 640 : W * 448;   // absolute col base of this wave
  constexpr int KT0 = LS ? W * 20 : W * 14;     // k-tile base
  constexpr int BD0 = LS ? 1024 : 256;          // end of s0 segment
  constexpr int BD1 = LS ? 1536 : 768;          // end of actx segment
  const int u8 = l & 15, rj = l >> 4;           // load mapping
  const int m = l & 15, kg = l >> 4;            // frag mapping

  u64 L0[8], L1[8];
  bh8_t f00, f01, f10, f11;

  auto load = [&](int c, u64* L, bh8_t& f0, bh8_t& f1) {
    const int c0 = CB + c * 64;                  // compile-time after unroll
    if (c0 >= BD0 && c0 < BD1) {                 // actx segment: f32 num, scale
      const float* base = numq + (c0 - BD0) + u8 * 4;
      #pragma unroll
      for (int j = 0; j < 8; ++j) {
        int row = 4 * j + rj;
        const float* fp = base + (size_t)row * kEmb;
        U64u a, b2; a.u = ald64(fp); b2.u = ald64(fp + 2);
        float s = invden[row];
        U64u pk;
        pk.s[0] = bf16rn(a.f2.x * s);  pk.s[1] = bf16rn(a.f2.y * s);
        pk.s[2] = bf16rn(b2.f2.x * s); pk.s[3] = bf16rn(b2.f2.y * s);
        L[j] = pk.u;
      }
    } else {
      const ushortt* bsrc; int stride; bool coh;
      if (c0 < BD0) { bsrc = s0 + c0;       stride = (LS ? 1024 : 256); coh = (LS == 1); }
      else          { bsrc = s2 + c0 - BD1; stride = 1024;              coh = true; }
      #pragma unroll
      for (int j = 0; j < 8; ++j) {
        const ushortt* ap = bsrc + (size_t)(4 * j + rj) * stride + u8 * 4;
        L[j] = coh ? ald64(ap) : *reinterpret_cast<const u64*>(ap);
      }
    }
    const bh8_t* p0 = reinterpret_cast<const bh8_t*>(pan + (size_t)(KT0 + c * 2) * 512 + l * 8);
    const bh8_t* p1 = reinterpret_cast<const bh8_t*>(pan + (size_t)(KT0 + c * 2 + 1) * 512 + l * 8);
    if (c >= NTC) {
      f0 = __builtin_nontemporal_load(p0);
      f1 = __builtin_nontemporal_load(p1);
    } else {
      f0 = *p0;
      f1 = *p1;
    }
  };
  auto stash = [&](int buf, u64* L) {
    #pragma unroll
    for (int j = 0; j < 8; ++j) {
      int row = 4 * j + rj;
      int sw = u8 ^ ((row & 7) << 1);
      *reinterpret_cast<u64*>(xstg + buf * 2048 + row * 64 + sw * 4) = L[j];
    }
  };
  auto consume = [&](int buf, bh8_t f0, bh8_t f1) {
    #pragma unroll
    for (int kt = 0; kt < 2; ++kt) {
      int sw = (2 * (kt * 4 + kg)) ^ ((m & 7) << 1);
      bh8_t a0 = *reinterpret_cast<const bh8_t*>(xstg + buf * 2048 + m * 64 + sw * 4);
      bh8_t a1 = *reinterpret_cast<const bh8_t*>(xstg + buf * 2048 + (16 + m) * 64 + sw * 4);
      bh8_t f = kt ? f1 : f0;
      z0 = __builtin_amdgcn_mfma_f32_16x16x32_bf16(a0, f, z0, 0, 0, 0);
      z1 = __builtin_amdgcn_mfma_f32_16x16x32_bf16(a1, f, z1, 0, 0, 0);
    }
  };

  load(0, L0, f00, f01);
  #pragma unroll
  for (int c = 0; c < NC; c += 2) {
    stash(0, L0);
    if (c + 1 < NC) load(c + 1, L1, f10, f11);
    consume(0, f00, f01);
    if (c + 1 < NC) {
      stash(1, L1);
      if (c + 2 < NC) load(c + 2, L0, f00, f01);
      consume(1, f10, f11);
    }
  }
}

extern "C" __global__ void __launch_bounds__(NTHR, 1)
decoder_kernel(const float* __restrict__ gmem, const float* __restrict__ dec,
               const unsigned char* __restrict__ mask,
               const float* __restrict__ pw1, const float* __restrict__ pw2,
               const float* __restrict__ awih, const float* __restrict__ awhh,
               const float* __restrict__ abih, const float* __restrict__ abhh,
               const float* __restrict__ qw, const float* __restrict__ mw,
               const float* __restrict__ cvw, const float* __restrict__ locw,
               const float* __restrict__ vw,
               const float* __restrict__ dwih, const float* __restrict__ dwhh,
               const float* __restrict__ dbih, const float* __restrict__ dbhh,
               const float* __restrict__ pjw, const float* __restrict__ pjb,
               const float* __restrict__ gw, const float* __restrict__ gb,
               float* __restrict__ out, float* __restrict__ ws, int useg)
{
  __shared__ SMem sm;
  __shared__ float s_invden[32];
  const int bk = blockIdx.x, tid = threadIdx.x;
  unsigned genv_f = 0, bcnt = 0;
  unsigned* bar = reinterpret_cast<unsigned*>(ws + OFF_BAR);
  unsigned* cntF = &bar[264 * 32];
  unsigned* genF = &bar[265 * 32];

  ushortt* PREBu = reinterpret_cast<ushortt*>(ws + OFF_PREB);
  ushortt* PROCMBu = reinterpret_cast<ushortt*>(ws + OFF_PROCMB);
  ushortt* QWTBu = reinterpret_cast<ushortt*>(ws + OFF_QWTB);
  float* LWT = ws + OFF_LWT;
  ushortt* AHBu = reinterpret_cast<ushortt*>(ws + OFF_AHB);
  ushortt* DHBu = reinterpret_cast<ushortt*>(ws + OFF_DHB);
  float* DH = ws + OFF_DH;
  float* AC = ws + OFF_AC;
  float* DC = ws + OFF_DC;
  float* ACTX = ws + OFF_ACTX;
  float* AWp = ws + OFF_AW;
  float* AWC = ws + OFF_AWC;
  float* PAW = ws + OFF_PAW;
  float* NUM = ws + OFF_NUM;
  float* DEN = ws + OFF_DEN;
  short* PANS = reinterpret_cast<short*>(ws + OFF_PAN);
  ushortt* GMB = reinterpret_cast<ushortt*>(ws + OFF_GMB);

  // ---------------- P0: zero state + QWTB + LWT ----------------
  for (int i = bk * NTHR + tid; i < STATE_SZ; i += NBLK * NTHR) (ws + OFF_STATE)[i] = 0.f;
  for (int i = bk * NTHR + tid; i < kAdim * kArnn; i += NBLK * NTHR)
    QWTBu[i] = bf16rn(qw[i]);
  for (int i = bk * NTHR + tid; i < kAdim * kNF; i += NBLK * NTHR) {
    int d = i >> 5, f = i & 31;
    LWT[d * 33 + f] = locw[i];
  }
  gbar_full(cntF, genF, genv_f);

  // ---------------- P1: den init, proc_mem (+bf16 gmem copy), prenet, panels ----------------
  if (bk == 0 && tid < 2 * kB) asf(&DEN[tid], 1.0f);
  for (int it = 0; it < 16; ++it) {
    int task0 = bk * 64 + it * 4;
    for (int i = tid; i < 2048; i += NTHR) {
      int pr = i >> 9, h = i & 511;
      sm.m.mem_s[pr][h] = gmem[(size_t)(task0 + pr) * kEmb + h];
    }
    __syncthreads();
    {
      int pr = tid >> 7, d = tid & 127;
      const float* mwr = mw + d * kEmb;
      float acc = 0.f;
      for (int h = 0; h < kEmb; ++h) acc = fmaf(sm.m.mem_s[pr][h], mwr[h], acc);
      PROCMBu[(size_t)(task0 + pr) * kAdim + d] = bf16rn(acc);
    }
    if (useg) {
      for (int i = tid; i < 2048; i += NTHR) {
        int pr = i >> 9, h = i & 511;
        GMB[(size_t)(task0 + pr) * kEmb + h] = bf16rn(sm.m.mem_s[pr][h]);
      }
    }
    __syncthreads();
  }
  for (int g = bk; g < 2000; g += NBLK) {
    int t_idx = g >> 2;
    int b0 = (g & 3) * 8;
    if (t_idx == 0) {
      for (int i = tid; i < 8 * kPre; i += NTHR)
        PREBu[(size_t)(b0 + (i >> 8)) * kPre + (i & 255)] = 0;
      continue;
    }
    for (int i = tid; i < 640; i += NTHR) {
      int bb = i / 80, m2 = i % 80;
      sm.p.x8[bb][m2] = dec[((size_t)(b0 + bb) * kNMel + m2) * kT + (t_idx - 1)];
    }
    __syncthreads();
    {
      int u = tid & 255, rep = tid >> 8;
      float acc[4] = {0.f, 0.f, 0.f, 0.f};
      for (int m2 = 0; m2 < 80; ++m2) {
        float w = pw1[u * kNMel + m2];
        #pragma unroll
        for (int r = 0; r < 4; ++r) acc[r] = fmaf(w, sm.p.x8[rep * 4 + r][m2], acc[r]);
      }
      #pragma unroll
      for (int r = 0; r < 4; ++r) sm.p.h1[rep * 4 + r][u] = fmaxf(acc[r], 0.f);
    }
    __syncthreads();
    {
      int u = tid & 255, rep = tid >> 8;
      float acc[4] = {0.f, 0.f, 0.f, 0.f};
      for (int k = 0; k < kPre; ++k) {
        float w = pw2[u * kPre + k];
        #pragma unroll
        for (int r = 0; r < 4; ++r) acc[r] = fmaf(w, sm.p.h1[rep * 4 + r][k], acc[r]);
      }
      #pragma unroll
      for (int r = 0; r < 4; ++r)
        PREBu[((size_t)t_idx * kB + b0 + rep * 4 + r) * kPre + u] = bf16rn(fmaxf(acc[r], 0.f));
    }
    __syncthreads();
  }
  {  // pack per-block bf16 weight panels in MFMA B-fragment order
    const int UNITS = NBLK * KT_ALL * 64;
    for (int u = bk * NTHR + tid; u < UNITS; u += NBLK * NTHR) {
      int bkk = u / (KT_ALL * 64);
      int rem = u - bkk * (KT_ALL * 64);
      int kta = rem >> 6, l = rem & 63;
      int lstm = (kta >= KT_A);
      int kt = lstm ? kta - KT_A : kta;
      int n = l & 15, kg = l >> 4;
      int r = (n >> 2) * 1024 + bkk * 4 + (n & 3);
      bh8_t v;
      #pragma unroll
      for (int j = 0; j < 8; ++j) {
        int k = kt * 32 + kg * 8 + j;
        float wv;
        if (!lstm) wv = (k < 768) ? awih[(size_t)r * 768 + k] : awhh[(size_t)r * 1024 + (k - 768)];
        else       wv = (k < 1536) ? dwih[(size_t)r * 1536 + k] : dwhh[(size_t)r * 1024 + (k - 1536)];
        v[j] = (short)bf16rn(wv);
      }
      *reinterpret_cast<bh8_t*>(PANS + (size_t)u * 8) = v;
    }
  }
  gbar_full(cntF, genF, genv_f);

  // ---------------- main scan: 2 barriers/step ----------------
  for (int t = 0; t <= kT; ++t) {
    const int p = t & 1, q = p ^ 1;
    float* nump = NUM + p * kB * kEmb;
    const float* numq = NUM + q * kB * kEmb;

    // ---- phase X: finalize(t-1) + aLSTM(t) + dLSTM(t-1) ----
    if (tid < kB) s_invden[tid] = 1.0f / alf(DEN + q * kB + tid);
    __syncthreads();
    if (t > 0 && tid < 64) {   // finalize step t-1 attention (own 64 elements)
      int idx = bk * 64 + tid;
      int b2 = idx >> 9;
      float invd = s_invden[b2];
      float av = PAW[idx] * invd;          // PAW block-private (plain)
      asf(&AWp[idx], av);
      asf(&AWC[idx], alf(&AWC[idx]) + av);
      asf(&ACTX[idx], alf(&numq[idx]) * invd);
    }
    if (t < kT) {
      if (tid < 64) asf(&nump[bk * 64 + tid], 0.f);
      if (bk == 0 && tid < kB) asf(DEN + p * kB + tid, 0.f);
    }
    {
      const int w8 = tid >> 6, l = tid & 63;
      fvec4 z0 = {0.f, 0.f, 0.f, 0.f}, z1 = z0;
      const ushortt* AHBq_ = AHBu + q * kB * kArnn;
      const ushortt* DHBp_ = DHBu + p * kB * kArnn;
      const ushortt* preb_t = PREBu + (size_t)t * kB * kPre;
      ushortt* xst = &sm.x1.xs[w8][0][0];
      const short* panb = PANS + (size_t)bk * (KT_ALL * 512);
      const short* pand = panb + KT_A * 512;
      if (w8 < 4) {
        if (t < kT) {
          switch (w8) {
            case 0: lstm_wave<0,0>(preb_t, AHBq_, numq, s_invden, panb, l, xst, z0, z1); break;
            case 1: lstm_wave<0,1>(preb_t, AHBq_, numq, s_invden, panb, l, xst, z0, z1); break;
            case 2: lstm_wave<0,2>(preb_t, AHBq_, numq, s_invden, panb, l, xst, z0, z1); break;
            default: lstm_wave<0,3>(preb_t, AHBq_, numq, s_invden, panb, l, xst, z0, z1); break;
          }
        }
      } else {
        if (t > 0) {
          switch (w8) {
            case 4: lstm_wave<1,0>(AHBq_, DHBp_, numq, s_invden, pand, l, xst, z0, z1); break;
            case 5: lstm_wave<1,1>(AHBq_, DHBp_, numq, s_invden, pand, l, xst, z0, z1); break;
            case 6: lstm_wave<1,2>(AHBq_, DHBp_, numq, s_invden, pand, l, xst, z0, z1); break;
            default: lstm_wave<1,3>(AHBq_, DHBp_, numq, s_invden, pand, l, xst, z0, z1); break;
          }
        }
      }
      __syncthreads();   // staging LDS dead; overlay with zred
      if (w8 < 4) {
        *reinterpret_cast<fvec4*>(&sm.x2.zra[w8][0][l][0]) = z0;
        *reinterpret_cast<fvec4*>(&sm.x2.zra[w8][1][l][0]) = z1;
      } else {
        *reinterpret_cast<fvec4*>(&sm.x2.zrd[w8 - 4][0][l][0]) = z0;
        *reinterpret_cast<fvec4*>(&sm.x2.zrd[w8 - 4][1][l][0]) = z1;
      }
    }
    __syncthreads();
    if (tid < 256) {  // gate epilogue
      const int ls = tid >> 7, uu = (tid >> 5) & 3, b = tid & 31;
      const bool go = (ls == 0) ? (t < kT) : (t > 0);
      if (go) {
        const int mt = b >> 4, mm = b & 15;
        const int lane_base = (mm >> 2) * 16, rr = mm & 3;
        float zg[4];
        #pragma unroll
        for (int g = 0; g < 4; ++g) {
          int ln = lane_base + g * 4 + uu;
          float s;
          if (ls == 0)
            s = sm.x2.zra[0][mt][ln][rr] + sm.x2.zra[1][mt][ln][rr]
              + sm.x2.zra[2][mt][ln][rr] + sm.x2.zra[3][mt][ln][rr];
          else
            s = sm.x2.zrd[0][mt][ln][rr] + sm.x2.zrd[1][mt][ln][rr]
              + sm.x2.zrd[2][mt][ln][rr] + sm.x2.zrd[3][mt][ln][rr];
          int rg = g * 1024 + bk * 4 + uu;
          s += (ls ? dbih[rg] + dbhh[rg] : abih[rg] + abhh[rg]);
          zg[g] = s;
        }
        float* cst = ls ? DC : AC;
        const int idx = b * kArnn + bk * 4 + uu;
        float c = sigf(zg[1]) * cst[idx] + sigf(zg[0]) * tanhfast(zg[2]);
        cst[idx] = c;
        float h = sigf(zg[3]) * tanhfast(c);
        if (ls) asf(&DH[q * kB * kArnn + idx], h);
        sm.x2.hb[ls][b][uu] = h;
      }
    }
    __syncthreads();
    if (tid < 64) {  // pack h -> bf16 state
      int ls = tid >> 5, b = tid & 31;
      bool go2 = ls ? (t > 0) : (t < kT);
      if (go2) {
        U64u pk;
        #pragma unroll
        for (int j = 0; j < 4; ++j) pk.s[j] = bf16rn(sm.x2.hb[ls][b][j]);
        ushortt* dst = (ls ? (DHBu + q * kB * kArnn) : (AHBu + p * kB * kArnn)) + b * kArnn + bk * 4;
        as64(dst, pk.u);
      }
    }
    gbar_light(bar, ++bcnt, bk, tid);

    if (t < kT) {
      // ---- phase B: attention step t (+ mel/gate of t-1) ----
      const int b = bk >> 3, sub = bk & 7, j0 = sub * 64;
      const int pbase = (sub == 0) ? 0 : 21 + (sub - 1) * 20;
      const int pcnt = (sub == 0) ? 21 : 20;
      const ushortt* AHBp_ = AHBu + p * kB * kArnn;
      // S1: staging
      if (tid < 256) {
        U64u v; v.u = ald64(AHBp_ + b * kArnn + tid * 4);
        #pragma unroll
        for (int j = 0; j < 4; ++j) sm.b.ahb_s[tid * 4 + j] = bf2f(v.s[j]);
      }
      for (int i = tid; i < 94; i += NTHR) {
        int jj = j0 - kPad + i;
        bool ok = (jj >= 0 && jj < kNctx);
        sm.b.aw_s[i] = ok ? alf(&AWp[b * kNctx + jj]) : 0.f;
        sm.b.awc_s[i] = ok ? alf(&AWC[b * kNctx + jj]) : 0.f;
      }
      for (int i = tid; i < kNF * 2 * kKS; i += NTHR) sm.b.cw[i] = cvw[i];
      for (int i = tid; i < kAdim * 33; i += NTHR) sm.b.lwt[i] = LWT[i];
      for (int i = tid; i < kAdim; i += NTHR) sm.b.vw_s[i] = vw[i];
      {  // proc_mem tile (bf16)
        const fvec4* src = reinterpret_cast<const fvec4*>(PROCMBu + (size_t)(b * kNctx + j0) * kAdim);
        fvec4* dst = reinterpret_cast<fvec4*>(sm.b.pm);
        for (int i = tid; i < 1024; i += NTHR) dst[i] = src[i];
      }
      if (sub < 4 && t > 0) {
        for (int i = tid; i < kArnn + kEmb; i += NTHR)
          sm.b.dhc[i] = (i < kArnn) ? alf(&DH[q * kB * kArnn + b * kArnn + i])
                                    : alf(&ACTX[b * kEmb + (i - kArnn)]);
      }
      __syncthreads();
      // S2: q partial (4-way K split, contiguous bf16 weights)
      {
        int d = tid & 127, qr = tid >> 7;
        const ushortt* wq = QWTBu + (size_t)d * kArnn + qr * 256;
        const float* ahs = sm.b.ahb_s + qr * 256;
        float acc = 0.f;
        #pragma unroll 4
        for (int h8 = 0; h8 < 32; ++h8) {
          U64u a, c2;
          a.u = *reinterpret_cast<const u64*>(wq + h8 * 8);
          c2.u = *reinterpret_cast<const u64*>(wq + h8 * 8 + 4);
          #pragma unroll
          for (int j = 0; j < 4; ++j) acc = fmaf(bf2f(a.s[j]), ahs[h8 * 8 + j], acc);
          #pragma unroll
          for (int j = 0; j < 4; ++j) acc = fmaf(bf2f(c2.s[j]), ahs[h8 * 8 + 4 + j], acc);
        }
        sm.b.psum[tid] = acc;
      }
      __syncthreads();
      // S3: q reduce + conv + projection partials
      if (tid < kAdim)
        sm.b.q_s[tid] = sm.b.psum[tid] + sm.b.psum[128 + tid]
                      + sm.b.psum[256 + tid] + sm.b.psum[384 + tid];
      {
        int j = tid >> 3, f0 = (tid & 7) * 4;
        #pragma unroll
        for (int fi = 0; fi < 4; ++fi) {
          int f = f0 + fi;
          const float* w0 = &sm.b.cw[f * 62];
          float s = 0.f;
          for (int k = 0; k < kKS; ++k)
            s = fmaf(sm.b.aw_s[j + k], w0[k], fmaf(sm.b.awc_s[j + k], w0[31 + k], s));
          sm.b.loc_s[j * 33 + f] = s;
        }
      }
      if (sub < 4 && t > 0 && tid < pcnt * 6) {
        int ol = tid / 6, kc = tid % 6, og = pbase + ol;
        const float* row = (og < kNMel) ? pjw + (size_t)og * (kArnn + kEmb) : gw;
        const float* x = sm.b.dhc + kc * 256;
        const float* r2 = row + kc * 256;
        float acc = 0.f;
        for (int k = 0; k < 256; ++k) acc = fmaf(r2[k], x[k], acc);
        sm.b.pprj[tid] = acc;
      }
      __syncthreads();
      // S4: energies + exp; projection finals
      {
        int j = tid >> 3, grp = tid & 7, jj = j0 + j;
        float pe = 0.f;
        #pragma unroll 4
        for (int dd = 0; dd < 16; ++dd) {
          int d = grp + 8 * dd;
          float l2 = 0.f;
          const float* ls2 = &sm.b.loc_s[j * 33];
          const float* lw2 = &sm.b.lwt[d * 33];
          #pragma unroll 8
          for (int f = 0; f < kNF; ++f) l2 = fmaf(ls2[f], lw2[f], l2);
          float x = sm.b.q_s[d] + bf2f(sm.b.pm[j * kAdim + d]) + l2;
          pe = fmaf(sm.b.vw_s[d], tanhfast(x), pe);
        }
        pe += __shfl_xor(pe, 1);
        pe += __shfl_xor(pe, 2);
        pe += __shfl_xor(pe, 4);
        if (grp == 0) {
          float pv = mask[b * kNctx + jj] ? 0.f : __expf(pe);
          sm.b.p_s[j] = pv;
          PAW[b * kNctx + jj] = pv;   // block-private
        }
      }
      if (sub < 4 && t > 0 && tid < pcnt) {
        int og = pbase + tid;
        float val = (og < kNMel) ? pjb[og] : gb[0];
        #pragma unroll
        for (int kc = 0; kc < 6; ++kc) val += sm.b.pprj[tid * 6 + kc];
        if (og < kNMel) out[((size_t)b * kNMel + og) * kT + (t - 1)] = val;
        else out[(size_t)kB * kNMel * kT + b * kT + (t - 1)] = val;
      }
      __syncthreads();
      // S5: denominator + numerator (parity-p buffers)
      if (tid < 64) {
        float v = sm.b.p_s[tid];
        #pragma unroll
        for (int o = 1; o < 64; o <<= 1) v += __shfl_xor(v, o);
        if (tid == 0) atomicAdd(DEN + p * kB + b, v);
      }
      if (useg) {
        const ushortt* memb = GMB + (size_t)(b * kNctx + j0) * kEmb + tid;
        float a0 = 0.f, a1 = 0.f, a2 = 0.f, a3 = 0.f;
        #pragma unroll 4
        for (int jj2 = 0; jj2 < 64; jj2 += 4) {
          a0 = fmaf(sm.b.p_s[jj2],     bf2f(__builtin_nontemporal_load(memb + (size_t)jj2 * kEmb)), a0);
          a1 = fmaf(sm.b.p_s[jj2 + 1], bf2f(__builtin_nontemporal_load(memb + (size_t)(jj2 + 1) * kEmb)), a1);
          a2 = fmaf(sm.b.p_s[jj2 + 2], bf2f(__builtin_nontemporal_load(memb + (size_t)(jj2 + 2) * kEmb)), a2);
          a3 = fmaf(sm.b.p_s[jj2 + 3], bf2f(__builtin_nontemporal_load(memb + (size_t)(jj2 + 3) * kEmb)), a3);
        }
        atomicAdd(&nump[b * kEmb + tid], (a0 + a1) + (a2 + a3));
      } else {
        const float* memb = gmem + (size_t)(b * kNctx + j0) * kEmb + tid;
        float a0 = 0.f, a1 = 0.f;
        #pragma unroll 8
        for (int jj2 = 0; jj2 < 64; jj2 += 2) {
          a0 = fmaf(sm.b.p_s[jj2], __builtin_nontemporal_load(memb + (size_t)jj2 * kEmb), a0);
          a1 = fmaf(sm.b.p_s[jj2 + 1], __builtin_nontemporal_load(memb + (size_t)(jj2 + 1) * kEmb), a1);
        }
        atomicAdd(&nump[b * kEmb + tid], a0 + a1);
      }
      gbar_light(bar, ++bcnt, bk, tid);
    }
  }

  // final projection t=499 (dh parity 1; ACTX(499) finalized in phase X(500))
  if (bk < kB) {
    const int b = bk;
    for (int i = tid; i < kArnn + kEmb; i += NTHR)
      sm.b.dhc[i] = (i < kArnn) ? alf(&DH[1 * kB * kArnn + b * kArnn + i])
                                : alf(&ACTX[b * kEmb + (i - kArnn)]);
    __syncthreads();
    if (tid < 486) {
      int ol = tid / 6, kc = tid % 6;
      const float* row = (ol < kNMel) ? pjw + (size_t)ol * (kArnn + kEmb) : gw;
      const float* x = sm.b.dhc + kc * 256;
      const float* r2 = row + kc * 256;
      float acc = 0.f;
      for (int k = 0; k < 256; ++k) acc = fmaf(r2[k], x[k], acc);
      sm.b.psum[tid] = acc;
    }
    __syncthreads();
    if (tid < 81) {
      float val = (tid < kNMel) ? pjb[tid] : gb[0];
      #pragma unroll
      for (int kc = 0; kc < 6; ++kc) val += sm.b.psum[tid * 6 + kc];
      if (tid < kNMel) out[((size_t)b * kNMel + tid) * kT + (kT - 1)] = val;
      else out[(size_t)kB * kNMel * kT + b * kT + (kT - 1)] = val;
    }
  }
}

extern "C" void kernel_launch(void* const* d_in, const int* in_sizes, int n_in,
                              void* d_out, int out_size, void* d_ws, size_t ws_size,
                              hipStream_t stream) {
  const float* gmem = (const float*)d_in[0];
  const float* dec = (const float*)d_in[1];
  const unsigned char* mask = (const unsigned char*)d_in[2];
  const float* pw1 = (const float*)d_in[3];
  const float* pw2 = (const float*)d_in[4];
  const float* awih = (const float*)d_in[5];
  const float* awhh = (const float*)d_in[6];
  const float* abih = (const float*)d_in[7];
  const float* abhh = (const float*)d_in[8];
  const float* qw = (const float*)d_in[9];
  const float* mw = (const float*)d_in[10];
  const float* cvw = (const float*)d_in[11];
  const float* locw = (const float*)d_in[12];
  const float* vw = (const float*)d_in[13];
  const float* dwih = (const float*)d_in[14];
  const float* dwhh = (const float*)d_in[15];
  const float* dbih = (const float*)d_in[16];
  const float* dbhh = (const float*)d_in[17];
  const float* pjw = (const float*)d_in[18];
  const float* pjb = (const float*)d_in[19];
  const float* gw = (const float*)d_in[20];
  const float* gb = (const float*)d_in[21];
  float* out = (float*)d_out;
  float* ws = (float*)d_ws;

  int useg = (ws_size >= (size_t)(OFF_GMB + GMB_SZ) * sizeof(float)) ? 1 : 0;

  // entire barrier region (flags + wake lines + init barrier) must start at 0
  hipMemsetAsync((char*)d_ws + (size_t)OFF_BAR * sizeof(float), 0,
                 (size_t)BAR_LINES * 128, stream);
  hipLaunchKernelGGL(decoder_kernel, dim3(NBLK), dim3(NTHR), 0, stream,
                     gmem, dec, mask, pw1, pw2, awih, awhh, abih, abhh, qw, mw,
                     cvw, locw, vw, dwih, dwhh, dbih, dbhh, pjw, pjb, gw, gb,
                     out, ws, useg);
}

// Round 10
// 39282.336 us; speedup vs baseline: 1.5218x; 1.0610x over previous
//
#include <hip/hip_runtime.h>

#define NBLK 256
#define NTHR 512

constexpr int kNMel = 80, kArnn = 1024, kAdim = 128, kEmb = 512, kPre = 256;
constexpr int kNF = 32, kKS = 31, kB = 32, kNctx = 512, kT = 500, kPad = 15;

constexpr int KT_A = 56;   // 1792/32 k-tiles (aLSTM: 256 prenet + 512 actx + 1024 ah)
constexpr int KT_D = 80;   // 2560/32 k-tiles (dLSTM: 1024 ah + 512 actx + 1024 dh)
constexpr int KT_ALL = KT_A + KT_D;

// ---- workspace layout (float offsets); GMB last so it is optional ----
constexpr int OFF_PREB   = 0;                                    // bf16 [500][32][256]
constexpr int OFF_PROCMB = OFF_PREB + kT * kB * kPre / 2;        // bf16 [32*512][128]
constexpr int OFF_QWTB   = OFF_PROCMB + kB * kNctx * kAdim / 2;  // bf16 [128][1024]
constexpr int OFF_LWT    = OFF_QWTB + kAdim * kArnn / 2;         // f32 [128*33]
constexpr int OFF_STATE  = OFF_LWT + kAdim * 33;
constexpr int OFF_AHB    = OFF_STATE;                            // bf16 [2][32][1024]
constexpr int OFF_DHB    = OFF_AHB + 2 * kB * kArnn / 2;         // bf16 [2][32][1024]
constexpr int OFF_DH     = OFF_DHB + 2 * kB * kArnn / 2;         // f32 [2][32][1024]
constexpr int OFF_AC     = OFF_DH + 2 * kB * kArnn;              // f32 [32][1024]
constexpr int OFF_DC     = OFF_AC + kB * kArnn;
constexpr int OFF_ACTX   = OFF_DC + kB * kArnn;                  // f32 [32][512]
constexpr int OFF_AW     = OFF_ACTX + kB * kEmb;                 // f32 [32][512]
constexpr int OFF_AWC    = OFF_AW + kB * kNctx;
constexpr int OFF_PAW    = OFF_AWC + kB * kNctx;                 // block-private
constexpr int OFF_NUM    = OFF_PAW + kB * kNctx;                 // f32 [2][32][512]
constexpr int OFF_DEN    = OFF_NUM + 2 * kB * kEmb;              // f32 [2][32]
constexpr int OFF_END    = OFF_DEN + 2 * kB;
constexpr int STATE_SZ   = OFF_END - OFF_STATE;
// barrier region: one 128B line per word. lines 0..255 arrival flags; 256..263 wake;
// 264/265 init barrier; 266..281 copy tickets [par][xcd].
constexpr int OFF_BAR    = OFF_END;
constexpr int BAR_LINES  = 282;
constexpr int OFF_PAN    = OFF_BAR + BAR_LINES * 32;             // bf16 panels
constexpr int PAN_SZ     = NBLK * KT_ALL * 256;                  // floats
// XCD-private state slots: [2 par][8 xcd] x (ah[32][1024] + dh[32][1024]) bf16
constexpr int SLOT_USH   = 131072;                               // ushorts per slot
constexpr int OFF_SLOT   = OFF_PAN + PAN_SZ;
constexpr int SLOT_SZF   = 2 * 8 * SLOT_USH / 2;                 // floats (1 Mi)
constexpr int OFF_GMB    = OFF_SLOT + SLOT_SZF;                  // bf16 [32*512][512] (optional)
constexpr int GMB_SZ     = kB * kNctx * kEmb / 2;

typedef __attribute__((ext_vector_type(4))) float fvec4;
typedef __attribute__((ext_vector_type(8))) short bh8_t;
typedef unsigned long long u64;
typedef unsigned short ushortt;

union U64u { u64 u; float2 f2; ushortt s[4]; };

union SMem {
  struct { ushortt ax[8 * 2048]; ushortt xs[8][2048]; } x1;          // 32+32 KB
  struct { float zra[4][2][64][4]; float zrd[4][2][64][4];
           float hb[2][32][4]; } x2;                                 // overlay after staging dead
  struct { float ahb_s[kArnn]; float vw_s[kAdim]; float psum[512]; float q_s[kAdim];
           float aw_s[96]; float awc_s[96]; float cw[kNF * 2 * kKS];
           float loc_s[64 * 33]; float p_s[64]; float lwt[kAdim * 33];
           float dhc[kArnn + kEmb]; float pprj[126];
           ushortt pm[64 * kAdim]; } b;
  struct { float x8[8][80]; float h1[8][256]; } p;
  struct { float mem_s[4][512]; } m;
};

__device__ __forceinline__ float sigf(float x) { return 1.0f / (1.0f + __expf(-x)); }
__device__ __forceinline__ float tanhfast(float x) { return 1.0f - 2.0f / (__expf(2.0f * x) + 1.0f); }

__device__ __forceinline__ ushortt bf16rn(float f) {
  unsigned u = __float_as_uint(f);
  unsigned r = (u + 0x7FFFu + ((u >> 16) & 1u)) >> 16;
  return (ushortt)r;
}
__device__ __forceinline__ float bf2f(ushortt v) {
  return __uint_as_float((unsigned)v << 16);
}

// relaxed agent-scope atomics (cross-XCD coherent via MALL)
__device__ __forceinline__ u64 ald64(const void* p) {
  return __hip_atomic_load((const u64*)p, __ATOMIC_RELAXED, __HIP_MEMORY_SCOPE_AGENT);
}
__device__ __forceinline__ float alf(const float* p) {
  return __hip_atomic_load(p, __ATOMIC_RELAXED, __HIP_MEMORY_SCOPE_AGENT);
}
__device__ __forceinline__ void asf(float* p, float v) {
  __hip_atomic_store(p, v, __ATOMIC_RELAXED, __HIP_MEMORY_SCOPE_AGENT);
}
__device__ __forceinline__ void as64(void* p, u64 v) {
  __hip_atomic_store((u64*)p, v, __ATOMIC_RELAXED, __HIP_MEMORY_SCOPE_AGENT);
}
__device__ __forceinline__ unsigned alu(const unsigned* p) {
  return __hip_atomic_load(p, __ATOMIC_RELAXED, __HIP_MEMORY_SCOPE_AGENT);
}
__device__ __forceinline__ void asu(unsigned* p, unsigned v) {
  __hip_atomic_store(p, v, __ATOMIC_RELAXED, __HIP_MEMORY_SCOPE_AGENT);
}

// L1-bypass load (sc0): coherent through the issuing XCD's own L2.
// Issue-only; caller must vm_drain() before using the result (HK pattern).
__device__ __forceinline__ u64 ld64_sc0(const ushortt* p) {
  u64 v;
  asm volatile("global_load_dwordx2 %0, %1, off sc0" : "=v"(v) : "v"(p));
  return v;
}
__device__ __forceinline__ void vm_drain() {
  asm volatile("s_waitcnt vmcnt(0)" ::: "memory");
  __builtin_amdgcn_sched_barrier(0);
}

// heavyweight init barrier (acq/rel) — used twice, before the scan
__device__ __forceinline__ void gbar_full(unsigned* cnt, unsigned* gen, unsigned& genv) {
  __syncthreads();
  if (threadIdx.x == 0) {
    __threadfence();
    unsigned arrived = __hip_atomic_fetch_add(cnt, 1u, __ATOMIC_ACQ_REL, __HIP_MEMORY_SCOPE_AGENT) + 1u;
    if (arrived == (unsigned)NBLK) {
      __hip_atomic_store(cnt, 0u, __ATOMIC_RELAXED, __HIP_MEMORY_SCOPE_AGENT);
      __hip_atomic_fetch_add(gen, 1u, __ATOMIC_ACQ_REL, __HIP_MEMORY_SCOPE_AGENT);
    } else {
      while (__hip_atomic_load(gen, __ATOMIC_ACQUIRE, __HIP_MEMORY_SCOPE_AGENT) == genv) {
        __builtin_amdgcn_s_sleep(2);
      }
    }
    ++genv;
  }
  __syncthreads();
}

// lightweight scan barrier: per-block flag lines; block 0 sweeps, fans out wake gen
__device__ __forceinline__ void gbar_light(unsigned* bar, unsigned target, int bk, int tid) {
  asm volatile("s_waitcnt vmcnt(0) lgkmcnt(0)" ::: "memory");
  __syncthreads();
  if (bk == 0) {
    if (tid < 64) {
      if (tid == 0) asm volatile("s_waitcnt vmcnt(0)" ::: "memory");
      unsigned i0 = (unsigned)tid * 4, i1 = i0 + 1, i2 = i0 + 2, i3 = i0 + 3;
      for (;;) {
        bool ok = true;
        if (i0 != 0) ok = ok && (alu(&bar[i0 * 32]) >= target);
        ok = ok && (alu(&bar[i1 * 32]) >= target);
        ok = ok && (alu(&bar[i2 * 32]) >= target);
        ok = ok && (alu(&bar[i3 * 32]) >= target);
        if (__all(ok)) break;
        __builtin_amdgcn_s_sleep(1);
      }
      if (tid < 8) asu(&bar[(256 + tid) * 32], target);
    }
  } else {
    if (tid == 0) {
      asm volatile("s_waitcnt vmcnt(0)" ::: "memory");
      asu(&bar[bk * 32], target);
      unsigned* wk = &bar[(256 + (bk & 7)) * 32];
      while (alu(wk) < target) __builtin_amdgcn_s_sleep(1);
    }
  }
  __syncthreads();
}

// ---- one wave's LSTM share: sequential per 64-col chunk, L2-hot sources ----
// seg per chunk: prenet (plain, global), actx (pre-staged swizzled LDS),
// ah/dh (XCD slot via sc0). Swizzle identical to R6.
template<int LS, int W>
__device__ __forceinline__ void lstm_wave(
    const ushortt* __restrict__ preb_t,
    const ushortt* __restrict__ slotAH, const ushortt* __restrict__ slotDH,
    const ushortt* __restrict__ axl, const short* __restrict__ pan,
    int l, ushortt* xs, fvec4& z0, fvec4& z1)
{
  constexpr int NC  = LS ? 10 : 7;
  constexpr int CB  = LS ? W * 640 : W * 448;
  constexpr int KT0 = LS ? W * 20 : W * 14;
  const int u8 = l & 15, rj = l >> 4;
  const int m = l & 15, kg = l >> 4;

  #pragma unroll
  for (int c = 0; c < NC; ++c) {
    const int c0 = CB + c * 64;
    const int ktA = KT0 + 2 * c;
    bh8_t f0 = *reinterpret_cast<const bh8_t*>(pan + (size_t)ktA * 512 + l * 8);
    bh8_t f1 = *reinterpret_cast<const bh8_t*>(pan + (size_t)(ktA + 1) * 512 + l * 8);
    const bool isAX = LS ? (c0 >= 1024 && c0 < 1536) : (c0 >= 256 && c0 < 768);
    if (isAX) {
      const int axch = LS ? ((c0 - 1024) >> 6) : ((c0 - 256) >> 6);
      const ushortt* base = axl + axch * 2048;
      #pragma unroll
      for (int kt = 0; kt < 2; ++kt) {
        int sw = (2 * (kt * 4 + kg)) ^ ((m & 7) << 1);
        bh8_t a0 = *reinterpret_cast<const bh8_t*>(base + m * 64 + sw * 4);
        bh8_t a1 = *reinterpret_cast<const bh8_t*>(base + (16 + m) * 64 + sw * 4);
        bh8_t f = kt ? f1 : f0;
        z0 = __builtin_amdgcn_mfma_f32_16x16x32_bf16(a0, f, z0, 0, 0, 0);
        z1 = __builtin_amdgcn_mfma_f32_16x16x32_bf16(a1, f, z1, 0, 0, 0);
      }
    } else {
      u64 L[8];
      if (!LS && c0 < 256) {          // prenet: plain global, compiler-tracked
        const ushortt* bsrc = preb_t + c0;
        #pragma unroll
        for (int j = 0; j < 8; ++j)
          L[j] = *reinterpret_cast<const u64*>(bsrc + (size_t)(4 * j + rj) * 256 + u8 * 4);
      } else {                        // slot ah/dh: sc0 loads, own-XCD L2
        const ushortt* bsrc;
        if (LS) bsrc = (c0 < 1024) ? (slotAH + c0) : (slotDH + (c0 - 1536));
        else    bsrc = slotAH + (c0 - 768);
        #pragma unroll
        for (int j = 0; j < 8; ++j)
          L[j] = ld64_sc0(bsrc + (size_t)(4 * j + rj) * 1024 + u8 * 4);
        vm_drain();
      }
      #pragma unroll
      for (int j = 0; j < 8; ++j) {
        int row = 4 * j + rj;
        int sw = u8 ^ ((row & 7) << 1);
        *reinterpret_cast<u64*>(xs + row * 64 + sw * 4) = L[j];
      }
      #pragma unroll
      for (int kt = 0; kt < 2; ++kt) {
        int sw = (2 * (kt * 4 + kg)) ^ ((m & 7) << 1);
        bh8_t a0 = *reinterpret_cast<const bh8_t*>(xs + m * 64 + sw * 4);
        bh8_t a1 = *reinterpret_cast<const bh8_t*>(xs + (16 + m) * 64 + sw * 4);
        bh8_t f = kt ? f1 : f0;
        z0 = __builtin_amdgcn_mfma_f32_16x16x32_bf16(a0, f, z0, 0, 0, 0);
        z1 = __builtin_amdgcn_mfma_f32_16x16x32_bf16(a1, f, z1, 0, 0, 0);
      }
    }
  }
}

extern "C" __global__ void __launch_bounds__(NTHR, 1)
decoder_kernel(const float* __restrict__ gmem, const float* __restrict__ dec,
               const unsigned char* __restrict__ mask,
               const float* __restrict__ pw1, const float* __restrict__ pw2,
               const float* __restrict__ awih, const float* __restrict__ awhh,
               const float* __restrict__ abih, const float* __restrict__ abhh,
               const float* __restrict__ qw, const float* __restrict__ mw,
               const float* __restrict__ cvw, const float* __restrict__ locw,
               const float* __restrict__ vw,
               const float* __restrict__ dwih, const float* __restrict__ dwhh,
               const float* __restrict__ dbih, const float* __restrict__ dbhh,
               const float* __restrict__ pjw, const float* __restrict__ pjb,
               const float* __restrict__ gw, const float* __restrict__ gb,
               float* __restrict__ out, float* __restrict__ ws, int useg)
{
  __shared__ SMem sm;
  __shared__ float s_invden[32];
  __shared__ int s_chunk;
  const int bk = blockIdx.x, tid = threadIdx.x;
  unsigned genv_f = 0, bcnt = 0;
  unsigned* bar = reinterpret_cast<unsigned*>(ws + OFF_BAR);
  unsigned* cntF = &bar[264 * 32];
  unsigned* genF = &bar[265 * 32];

  unsigned myxcd;
  asm("s_getreg_b32 %0, hwreg(HW_REG_XCC_ID)" : "=s"(myxcd));
  myxcd &= 7u;

  ushortt* PREBu = reinterpret_cast<ushortt*>(ws + OFF_PREB);
  ushortt* PROCMBu = reinterpret_cast<ushortt*>(ws + OFF_PROCMB);
  ushortt* QWTBu = reinterpret_cast<ushortt*>(ws + OFF_QWTB);
  float* LWT = ws + OFF_LWT;
  ushortt* AHBu = reinterpret_cast<ushortt*>(ws + OFF_AHB);
  ushortt* DHBu = reinterpret_cast<ushortt*>(ws + OFF_DHB);
  float* DH = ws + OFF_DH;
  float* AC = ws + OFF_AC;
  float* DC = ws + OFF_DC;
  float* ACTX = ws + OFF_ACTX;
  float* AWp = ws + OFF_AW;
  float* AWC = ws + OFF_AWC;
  float* PAW = ws + OFF_PAW;
  float* NUM = ws + OFF_NUM;
  float* DEN = ws + OFF_DEN;
  short* PANS = reinterpret_cast<short*>(ws + OFF_PAN);
  ushortt* SLOTu = reinterpret_cast<ushortt*>(ws + OFF_SLOT);
  ushortt* GMB = reinterpret_cast<ushortt*>(ws + OFF_GMB);

  // ---------------- P0: zero state + slots + QWTB + LWT ----------------
  for (int i = bk * NTHR + tid; i < STATE_SZ; i += NBLK * NTHR) (ws + OFF_STATE)[i] = 0.f;
  for (int i = bk * NTHR + tid; i < SLOT_SZF; i += NBLK * NTHR) (ws + OFF_SLOT)[i] = 0.f;
  for (int i = bk * NTHR + tid; i < kAdim * kArnn; i += NBLK * NTHR)
    QWTBu[i] = bf16rn(qw[i]);
  for (int i = bk * NTHR + tid; i < kAdim * kNF; i += NBLK * NTHR) {
    int d = i >> 5, f = i & 31;
    LWT[d * 33 + f] = locw[i];
  }
  gbar_full(cntF, genF, genv_f);

  // ---------------- P1: den init, proc_mem (+bf16 gmem copy), prenet, panels ----------------
  if (bk == 0 && tid < 2 * kB) asf(&DEN[tid], 1.0f);
  for (int it = 0; it < 16; ++it) {
    int task0 = bk * 64 + it * 4;
    for (int i = tid; i < 2048; i += NTHR) {
      int pr = i >> 9, h = i & 511;
      sm.m.mem_s[pr][h] = gmem[(size_t)(task0 + pr) * kEmb + h];
    }
    __syncthreads();
    {
      int pr = tid >> 7, d = tid & 127;
      const float* mwr = mw + d * kEmb;
      float acc = 0.f;
      for (int h = 0; h < kEmb; ++h) acc = fmaf(sm.m.mem_s[pr][h], mwr[h], acc);
      PROCMBu[(size_t)(task0 + pr) * kAdim + d] = bf16rn(acc);
    }
    if (useg) {
      for (int i = tid; i < 2048; i += NTHR) {
        int pr = i >> 9, h = i & 511;
        GMB[(size_t)(task0 + pr) * kEmb + h] = bf16rn(sm.m.mem_s[pr][h]);
      }
    }
    __syncthreads();
  }
  for (int g = bk; g < 2000; g += NBLK) {
    int t_idx = g >> 2;
    int b0 = (g & 3) * 8;
    if (t_idx == 0) {
      for (int i = tid; i < 8 * kPre; i += NTHR)
        PREBu[(size_t)(b0 + (i >> 8)) * kPre + (i & 255)] = 0;
      continue;
    }
    for (int i = tid; i < 640; i += NTHR) {
      int bb = i / 80, m2 = i % 80;
      sm.p.x8[bb][m2] = dec[((size_t)(b0 + bb) * kNMel + m2) * kT + (t_idx - 1)];
    }
    __syncthreads();
    {
      int u = tid & 255, rep = tid >> 8;
      float acc[4] = {0.f, 0.f, 0.f, 0.f};
      for (int m2 = 0; m2 < 80; ++m2) {
        float w = pw1[u * kNMel + m2];
        #pragma unroll
        for (int r = 0; r < 4; ++r) acc[r] = fmaf(w, sm.p.x8[rep * 4 + r][m2], acc[r]);
      }
      #pragma unroll
      for (int r = 0; r < 4; ++r) sm.p.h1[rep * 4 + r][u] = fmaxf(acc[r], 0.f);
    }
    __syncthreads();
    {
      int u = tid & 255, rep = tid >> 8;
      float acc[4] = {0.f, 0.f, 0.f, 0.f};
      for (int k = 0; k < kPre; ++k) {
        float w = pw2[u * kPre + k];
        #pragma unroll
        for (int r = 0; r < 4; ++r) acc[r] = fmaf(w, sm.p.h1[rep * 4 + r][k], acc[r]);
      }
      #pragma unroll
      for (int r = 0; r < 4; ++r)
        PREBu[((size_t)t_idx * kB + b0 + rep * 4 + r) * kPre + u] = bf16rn(fmaxf(acc[r], 0.f));
    }
    __syncthreads();
  }
  {  // pack per-block bf16 weight panels in MFMA B-fragment order
    const int UNITS = NBLK * KT_ALL * 64;
    for (int u = bk * NTHR + tid; u < UNITS; u += NBLK * NTHR) {
      int bkk = u / (KT_ALL * 64);
      int rem = u - bkk * (KT_ALL * 64);
      int kta = rem >> 6, l = rem & 63;
      int lstm = (kta >= KT_A);
      int kt = lstm ? kta - KT_A : kta;
      int n = l & 15, kg = l >> 4;
      int r = (n >> 2) * 1024 + bkk * 4 + (n & 3);
      bh8_t v;
      #pragma unroll
      for (int j = 0; j < 8; ++j) {
        int k = kt * 32 + kg * 8 + j;
        float wv;
        if (!lstm) wv = (k < 768) ? awih[(size_t)r * 768 + k] : awhh[(size_t)r * 1024 + (k - 768)];
        else       wv = (k < 1536) ? dwih[(size_t)r * 1536 + k] : dwhh[(size_t)r * 1024 + (k - 1536)];
        v[j] = (short)bf16rn(wv);
      }
      *reinterpret_cast<bh8_t*>(PANS + (size_t)u * 8) = v;
    }
  }
  gbar_full(cntF, genF, genv_f);

  // ---------------- main scan: 2 barriers/step ----------------
  for (int t = 0; t <= kT; ++t) {
    const int p = t & 1, q = p ^ 1;
    float* nump = NUM + p * kB * kEmb;
    const float* numq = NUM + q * kB * kEmb;

    // ---- phase X: finalize(t-1) + ax pre-stage + aLSTM(t) + dLSTM(t-1) ----
    if (tid < kB) s_invden[tid] = 1.0f / alf(DEN + q * kB + tid);
    __syncthreads();
    if (t > 0 && tid < 64) {
      int idx = bk * 64 + tid;
      int b2 = idx >> 9;
      float invd = s_invden[b2];
      float av = PAW[idx] * invd;
      asf(&AWp[idx], av);
      asf(&AWC[idx], alf(&AWC[idx]) + av);
      asf(&ACTX[idx], alf(&numq[idx]) * invd);
    }
    if (t < kT) {
      if (tid < 64) asf(&nump[bk * 64 + tid], 0.f);
      if (bk == 0 && tid < kB) asf(DEN + p * kB + tid, 0.f);
    }
    if (bk == 0 && tid < 8) asu(&bar[(266 + q * 8 + tid) * 32], 0u);  // reset tickets for B(t)
    {  // ax pre-stage: numq * invden -> swizzled bf16 LDS (8 chunks x [32][64])
      ushortt* axl = sm.x1.ax;
      for (int task = tid; task < 2048; task += NTHR) {
        int ch = task >> 8, r = (task >> 3) & 31, g8 = task & 7;
        const float* np = numq + (size_t)r * 512 + ch * 64 + g8 * 8;
        float s = s_invden[r];
        U64u a, b2, c2, d2;
        a.u = ald64(np); b2.u = ald64(np + 2); c2.u = ald64(np + 4); d2.u = ald64(np + 6);
        U64u p0, p1;
        p0.s[0] = bf16rn(a.f2.x * s);  p0.s[1] = bf16rn(a.f2.y * s);
        p0.s[2] = bf16rn(b2.f2.x * s); p0.s[3] = bf16rn(b2.f2.y * s);
        p1.s[0] = bf16rn(c2.f2.x * s); p1.s[1] = bf16rn(c2.f2.y * s);
        p1.s[2] = bf16rn(d2.f2.x * s); p1.s[3] = bf16rn(d2.f2.y * s);
        ushortt* base = axl + ch * 2048 + r * 64;
        int x = (r & 7) << 1;
        *reinterpret_cast<u64*>(base + ((2 * g8) ^ x) * 4) = p0.u;
        *reinterpret_cast<u64*>(base + ((2 * g8 + 1) ^ x) * 4) = p1.u;
      }
    }
    __syncthreads();
    {
      const int w8 = tid >> 6, l = tid & 63;
      fvec4 z0 = {0.f, 0.f, 0.f, 0.f}, z1 = z0;
      const ushortt* slotAH = SLOTu + ((size_t)p * 8 + myxcd) * SLOT_USH;
      const ushortt* slotDH = slotAH + 65536;
      const ushortt* preb_t = PREBu + (size_t)t * kB * kPre;
      const short* panb = PANS + (size_t)bk * (KT_ALL * 512);
      const short* pand = panb + KT_A * 512;
      ushortt* xs = &sm.x1.xs[w8][0];
      ushortt* axl = sm.x1.ax;
      if (w8 < 4) {
        if (t < kT) {
          switch (w8) {
            case 0: lstm_wave<0,0>(preb_t, slotAH, slotDH, axl, panb, l, xs, z0, z1); break;
            case 1: lstm_wave<0,1>(preb_t, slotAH, slotDH, axl, panb, l, xs, z0, z1); break;
            case 2: lstm_wave<0,2>(preb_t, slotAH, slotDH, axl, panb, l, xs, z0, z1); break;
            default: lstm_wave<0,3>(preb_t, slotAH, slotDH, axl, panb, l, xs, z0, z1); break;
          }
        }
      } else {
        if (t > 0) {
          switch (w8) {
            case 4: lstm_wave<1,0>(preb_t, slotAH, slotDH, axl, pand, l, xs, z0, z1); break;
            case 5: lstm_wave<1,1>(preb_t, slotAH, slotDH, axl, pand, l, xs, z0, z1); break;
            case 6: lstm_wave<1,2>(preb_t, slotAH, slotDH, axl, pand, l, xs, z0, z1); break;
            default: lstm_wave<1,3>(preb_t, slotAH, slotDH, axl, pand, l, xs, z0, z1); break;
          }
        }
      }
      __syncthreads();   // staging LDS dead; overlay with zred
      if (w8 < 4) {
        *reinterpret_cast<fvec4*>(&sm.x2.zra[w8][0][l][0]) = z0;
        *reinterpret_cast<fvec4*>(&sm.x2.zra[w8][1][l][0]) = z1;
      } else {
        *reinterpret_cast<fvec4*>(&sm.x2.zrd[w8 - 4][0][l][0]) = z0;
        *reinterpret_cast<fvec4*>(&sm.x2.zrd[w8 - 4][1][l][0]) = z1;
      }
    }
    __syncthreads();
    if (tid < 256) {  // gate epilogue
      const int ls = tid >> 7, uu = (tid >> 5) & 3, b = tid & 31;
      const bool go = (ls == 0) ? (t < kT) : (t > 0);
      if (go) {
        const int mt = b >> 4, mm = b & 15;
        const int lane_base = (mm >> 2) * 16, rr = mm & 3;
        float zg[4];
        #pragma unroll
        for (int g = 0; g < 4; ++g) {
          int ln = lane_base + g * 4 + uu;
          float s;
          if (ls == 0)
            s = sm.x2.zra[0][mt][ln][rr] + sm.x2.zra[1][mt][ln][rr]
              + sm.x2.zra[2][mt][ln][rr] + sm.x2.zra[3][mt][ln][rr];
          else
            s = sm.x2.zrd[0][mt][ln][rr] + sm.x2.zrd[1][mt][ln][rr]
              + sm.x2.zrd[2][mt][ln][rr] + sm.x2.zrd[3][mt][ln][rr];
          int rg = g * 1024 + bk * 4 + uu;
          s += (ls ? dbih[rg] + dbhh[rg] : abih[rg] + abhh[rg]);
          zg[g] = s;
        }
        float* cst = ls ? DC : AC;
        const int idx = b * kArnn + bk * 4 + uu;
        float c = sigf(zg[1]) * cst[idx] + sigf(zg[0]) * tanhfast(zg[2]);
        cst[idx] = c;
        float h = sigf(zg[3]) * tanhfast(c);
        if (ls) asf(&DH[q * kB * kArnn + idx], h);
        sm.x2.hb[ls][b][uu] = h;
      }
    }
    __syncthreads();
    if (tid < 64) {  // pack h -> bf16 state
      int ls = tid >> 5, b = tid & 31;
      bool go2 = ls ? (t > 0) : (t < kT);
      if (go2) {
        U64u pk;
        #pragma unroll
        for (int j = 0; j < 4; ++j) pk.s[j] = bf16rn(sm.x2.hb[ls][b][j]);
        ushortt* dst = (ls ? (DHBu + q * kB * kArnn) : (AHBu + p * kB * kArnn)) + b * kArnn + bk * 4;
        as64(dst, pk.u);
      }
    }
    gbar_light(bar, ++bcnt, bk, tid);

    if (t < kT) {
      // ---- phase B: attention step t (+ mel/gate of t-1) + slot copy for X(t+1) ----
      const int b = bk >> 3, sub = bk & 7, j0 = sub * 64;
      const int pbase = (sub == 0) ? 0 : 21 + (sub - 1) * 20;
      const int pcnt = (sub == 0) ? 21 : 20;
      const ushortt* AHBp_ = AHBu + p * kB * kArnn;
      if (tid == 0) {   // claim one state-row chunk of this XCD's slot copy
        unsigned a = __hip_atomic_fetch_add(&bar[(266 + q * 8 + (int)myxcd) * 32], 1u,
                                            __ATOMIC_RELAXED, __HIP_MEMORY_SCOPE_AGENT);
        s_chunk = (int)a;
      }
      // S1: staging
      if (tid < 256) {
        U64u v; v.u = ald64(AHBp_ + b * kArnn + tid * 4);
        #pragma unroll
        for (int j = 0; j < 4; ++j) sm.b.ahb_s[tid * 4 + j] = bf2f(v.s[j]);
      }
      for (int i = tid; i < 94; i += NTHR) {
        int jj = j0 - kPad + i;
        bool ok = (jj >= 0 && jj < kNctx);
        sm.b.aw_s[i] = ok ? alf(&AWp[b * kNctx + jj]) : 0.f;
        sm.b.awc_s[i] = ok ? alf(&AWC[b * kNctx + jj]) : 0.f;
      }
      for (int i = tid; i < kNF * 2 * kKS; i += NTHR) sm.b.cw[i] = cvw[i];
      for (int i = tid; i < kAdim * 33; i += NTHR) sm.b.lwt[i] = LWT[i];
      for (int i = tid; i < kAdim; i += NTHR) sm.b.vw_s[i] = vw[i];
      {  // proc_mem tile (bf16)
        const fvec4* src = reinterpret_cast<const fvec4*>(PROCMBu + (size_t)(b * kNctx + j0) * kAdim);
        fvec4* dst = reinterpret_cast<fvec4*>(sm.b.pm);
        for (int i = tid; i < 1024; i += NTHR) dst[i] = src[i];
      }
      if (sub < 4 && t > 0) {
        for (int i = tid; i < kArnn + kEmb; i += NTHR)
          sm.b.dhc[i] = (i < kArnn) ? alf(&DH[q * kB * kArnn + b * kArnn + i])
                                    : alf(&ACTX[b * kEmb + (i - kArnn)]);
      }
      __syncthreads();
      // slot copy: ah_t (AHB[p]) + dh_{t-1} (DHB[q]) row s_chunk -> SLOT[q][myxcd]
      if (s_chunk < 32) {
        ushortt* sb = SLOTu + ((size_t)q * 8 + myxcd) * SLOT_USH;
        if (tid < 256) {
          u64 v = ald64(AHBu + (size_t)p * kB * kArnn + s_chunk * 1024 + tid * 4);
          *reinterpret_cast<u64*>(sb + (size_t)s_chunk * 1024 + tid * 4) = v;
        } else {
          int j = tid - 256;
          u64 v = ald64(DHBu + (size_t)q * kB * kArnn + s_chunk * 1024 + j * 4);
          *reinterpret_cast<u64*>(sb + 65536 + (size_t)s_chunk * 1024 + j * 4) = v;
        }
      }
      // S2: q partial (4-way K split, contiguous bf16 weights)
      {
        int d = tid & 127, qr = tid >> 7;
        const ushortt* wq = QWTBu + (size_t)d * kArnn + qr * 256;
        const float* ahs = sm.b.ahb_s + qr * 256;
        float acc = 0.f;
        #pragma unroll 4
        for (int h8 = 0; h8 < 32; ++h8) {
          U64u a, c2;
          a.u = *reinterpret_cast<const u64*>(wq + h8 * 8);
          c2.u = *reinterpret_cast<const u64*>(wq + h8 * 8 + 4);
          #pragma unroll
          for (int j = 0; j < 4; ++j) acc = fmaf(bf2f(a.s[j]), ahs[h8 * 8 + j], acc);
          #pragma unroll
          for (int j = 0; j < 4; ++j) acc = fmaf(bf2f(c2.s[j]), ahs[h8 * 8 + 4 + j], acc);
        }
        sm.b.psum[tid] = acc;
      }
      __syncthreads();
      // S3: q reduce + conv + projection partials
      if (tid < kAdim)
        sm.b.q_s[tid] = sm.b.psum[tid] + sm.b.psum[128 + tid]
                      + sm.b.psum[256 + tid] + sm.b.psum[384 + tid];
      {
        int j = tid >> 3, f0 = (tid & 7) * 4;
        #pragma unroll
        for (int fi = 0; fi < 4; ++fi) {
          int f = f0 + fi;
          const float* w0 = &sm.b.cw[f * 62];
          float s = 0.f;
          for (int k = 0; k < kKS; ++k)
            s = fmaf(sm.b.aw_s[j + k], w0[k], fmaf(sm.b.awc_s[j + k], w0[31 + k], s));
          sm.b.loc_s[j * 33 + f] = s;
        }
      }
      if (sub < 4 && t > 0 && tid < pcnt * 6) {
        int ol = tid / 6, kc = tid % 6, og = pbase + ol;
        const float* row = (og < kNMel) ? pjw + (size_t)og * (kArnn + kEmb) : gw;
        const float* x = sm.b.dhc + kc * 256;
        const float* r2 = row + kc * 256;
        float acc = 0.f;
        for (int k = 0; k < 256; ++k) acc = fmaf(r2[k], x[k], acc);
        sm.b.pprj[tid] = acc;
      }
      __syncthreads();
      // S4: energies + exp; projection finals
      {
        int j = tid >> 3, grp = tid & 7, jj = j0 + j;
        float pe = 0.f;
        #pragma unroll 4
        for (int dd = 0; dd < 16; ++dd) {
          int d = grp + 8 * dd;
          float l2 = 0.f;
          const float* ls2 = &sm.b.loc_s[j * 33];
          const float* lw2 = &sm.b.lwt[d * 33];
          #pragma unroll 8
          for (int f = 0; f < kNF; ++f) l2 = fmaf(ls2[f], lw2[f], l2);
          float x = sm.b.q_s[d] + bf2f(sm.b.pm[j * kAdim + d]) + l2;
          pe = fmaf(sm.b.vw_s[d], tanhfast(x), pe);
        }
        pe += __shfl_xor(pe, 1);
        pe += __shfl_xor(pe, 2);
        pe += __shfl_xor(pe, 4);
        if (grp == 0) {
          float pv = mask[b * kNctx + jj] ? 0.f : __expf(pe);
          sm.b.p_s[j] = pv;
          PAW[b * kNctx + jj] = pv;   // block-private
        }
      }
      if (sub < 4 && t > 0 && tid < pcnt) {
        int og = pbase + tid;
        float val = (og < kNMel) ? pjb[og] : gb[0];
        #pragma unroll
        for (int kc = 0; kc < 6; ++kc) val += sm.b.pprj[tid * 6 + kc];
        if (og < kNMel) out[((size_t)b * kNMel + og) * kT + (t - 1)] = val;
        else out[(size_t)kB * kNMel * kT + b * kT + (t - 1)] = val;
      }
      __syncthreads();
      // S5: denominator + numerator (parity-p buffers)
      if (tid < 64) {
        float v = sm.b.p_s[tid];
        #pragma unroll
        for (int o = 1; o < 64; o <<= 1) v += __shfl_xor(v, o);
        if (tid == 0) atomicAdd(DEN + p * kB + b, v);
      }
      if (useg) {
        const ushortt* memb = GMB + (size_t)(b * kNctx + j0) * kEmb + tid;
        float a0 = 0.f, a1 = 0.f, a2 = 0.f, a3 = 0.f;
        #pragma unroll 4
        for (int jj2 = 0; jj2 < 64; jj2 += 4) {
          a0 = fmaf(sm.b.p_s[jj2],     bf2f(memb[(size_t)jj2 * kEmb]), a0);
          a1 = fmaf(sm.b.p_s[jj2 + 1], bf2f(memb[(size_t)(jj2 + 1) * kEmb]), a1);
          a2 = fmaf(sm.b.p_s[jj2 + 2], bf2f(memb[(size_t)(jj2 + 2) * kEmb]), a2);
          a3 = fmaf(sm.b.p_s[jj2 + 3], bf2f(memb[(size_t)(jj2 + 3) * kEmb]), a3);
        }
        atomicAdd(&nump[b * kEmb + tid], (a0 + a1) + (a2 + a3));
      } else {
        const float* memb = gmem + (size_t)(b * kNctx + j0) * kEmb + tid;
        float a0 = 0.f, a1 = 0.f;
        #pragma unroll 8
        for (int jj2 = 0; jj2 < 64; jj2 += 2) {
          a0 = fmaf(sm.b.p_s[jj2], memb[(size_t)jj2 * kEmb], a0);
          a1 = fmaf(sm.b.p_s[jj2 + 1], memb[(size_t)(jj2 + 1) * kEmb], a1);
        }
        atomicAdd(&nump[b * kEmb + tid], a0 + a1);
      }
      gbar_light(bar, ++bcnt, bk, tid);
    }
  }

  // final projection t=499 (dh parity 1; ACTX(499) finalized in phase X(500))
  if (bk < kB) {
    const int b = bk;
    for (int i = tid; i < kArnn + kEmb; i += NTHR)
      sm.b.dhc[i] = (i < kArnn) ? alf(&DH[1 * kB * kArnn + b * kArnn + i])
                                : alf(&ACTX[b * kEmb + (i - kArnn)]);
    __syncthreads();
    if (tid < 486) {
      int ol = tid / 6, kc = tid % 6;
      const float* row = (ol < kNMel) ? pjw + (size_t)ol * (kArnn + kEmb) : gw;
      const float* x = sm.b.dhc + kc * 256;
      const float* r2 = row + kc * 256;
      float acc = 0.f;
      for (int k = 0; k < 256; ++k) acc = fmaf(r2[k], x[k], acc);
      sm.b.psum[tid] = acc;
    }
    __syncthreads();
    if (tid < 81) {
      float val = (tid < kNMel) ? pjb[tid] : gb[0];
      #pragma unroll
      for (int kc = 0; kc < 6; ++kc) val += sm.b.psum[tid * 6 + kc];
      if (tid < kNMel) out[((size_t)b * kNMel + tid) * kT + (kT - 1)] = val;
      else out[(size_t)kB * kNMel * kT + b * kT + (kT - 1)] = val;
    }
  }
}

extern "C" void kernel_launch(void* const* d_in, const int* in_sizes, int n_in,
                              void* d_out, int out_size, void* d_ws, size_t ws_size,
                              hipStream_t stream) {
  const float* gmem = (const float*)d_in[0];
  const float* dec = (const float*)d_in[1];
  const unsigned char* mask = (const unsigned char*)d_in[2];
  const float* pw1 = (const float*)d_in[3];
  const float* pw2 = (const float*)d_in[4];
  const float* awih = (const float*)d_in[5];
  const float* awhh = (const float*)d_in[6];
  const float* abih = (const float*)d_in[7];
  const float* abhh = (const float*)d_in[8];
  const float* qw = (const float*)d_in[9];
  const float* mw = (const float*)d_in[10];
  const float* cvw = (const float*)d_in[11];
  const float* locw = (const float*)d_in[12];
  const float* vw = (const float*)d_in[13];
  const float* dwih = (const float*)d_in[14];
  const float* dwhh = (const float*)d_in[15];
  const float* dbih = (const float*)d_in[16];
  const float* dbhh = (const float*)d_in[17];
  const float* pjw = (const float*)d_in[18];
  const float* pjb = (const float*)d_in[19];
  const float* gw = (const float*)d_in[20];
  const float* gb = (const float*)d_in[21];
  float* out = (float*)d_out;
  float* ws = (float*)d_ws;

  int useg = (ws_size >= (size_t)(OFF_GMB + GMB_SZ) * sizeof(float)) ? 1 : 0;

  // entire barrier region (flags + wake + init + tickets) must start at 0
  hipMemsetAsync((char*)d_ws + (size_t)OFF_BAR * sizeof(float), 0,
                 (size_t)BAR_LINES * 128, stream);
  hipLaunchKernelGGL(decoder_kernel, dim3(NBLK), dim3(NTHR), 0, stream,
                     gmem, dec, mask, pw1, pw2, awih, awhh, abih, abhh, qw, mw,
                     cvw, locw, vw, dwih, dwhh, dbih, dbhh, pjw, pjb, gw, gb,
                     out, ws, useg);
}